// Round 1
// baseline (512.594 us; speedup 1.0000x reference)
//
#include <hip/hip_runtime.h>

#define N_NODES 40000
#define N_EDGES 640000
#define IN_DIM 256
#define HID 128

// ---------------- CSR build ----------------

__global__ void deg_count(const int* __restrict__ dst, int* __restrict__ deg, int E) {
    int e = blockIdx.x * 256 + threadIdx.x;
    if (e < E) atomicAdd(&deg[dst[e]], 1);
}

__global__ __launch_bounds__(1024) void scan_kernel(const int* __restrict__ deg,
                                                    int* __restrict__ row_off,
                                                    int* __restrict__ cursor, int N) {
    __shared__ int sh[1024];
    int tid = threadIdx.x;
    const int CH = (N + 1023) >> 10;  // elements per thread
    int beg = tid * CH;
    int end = min(N, beg + CH);
    int tot = 0;
    for (int i = beg; i < end; ++i) tot += deg[i];
    sh[tid] = tot;
    __syncthreads();
    for (int off = 1; off < 1024; off <<= 1) {
        int v = (tid >= off) ? sh[tid - off] : 0;
        __syncthreads();
        sh[tid] += v;
        __syncthreads();
    }
    int run = sh[tid] - tot;  // exclusive prefix
    for (int i = beg; i < end; ++i) {
        row_off[i] = run;
        cursor[i] = run;
        run += deg[i];
    }
    if (tid == 1023) row_off[N] = sh[1023];
}

__global__ void scatter_edges(const int* __restrict__ src, const int* __restrict__ dst,
                              int* __restrict__ cursor, int* __restrict__ csr, int E) {
    int e = blockIdx.x * 256 + threadIdx.x;
    if (e < E) {
        int p = atomicAdd(&cursor[dst[e]], 1);
        csr[p] = src[e];
    }
}

// ---------------- mean aggregation: one wave per node ----------------

__global__ __launch_bounds__(256) void agg_mean(const float* __restrict__ h,
                                                const int* __restrict__ row_off,
                                                const int* __restrict__ csr,
                                                float* __restrict__ out, int N) {
    int node = blockIdx.x * 4 + (threadIdx.x >> 6);
    if (node >= N) return;
    int lane = threadIdx.x & 63;
    int beg = row_off[node], end = row_off[node + 1];
    float ax = 0.f, ay = 0.f;
    int e = beg;
    for (; e + 1 < end; e += 2) {
        int s0 = csr[e], s1 = csr[e + 1];
        float2 v0 = *(const float2*)&h[(size_t)s0 * HID + lane * 2];
        float2 v1 = *(const float2*)&h[(size_t)s1 * HID + lane * 2];
        ax += v0.x + v1.x;
        ay += v0.y + v1.y;
    }
    if (e < end) {
        int s0 = csr[e];
        float2 v0 = *(const float2*)&h[(size_t)s0 * HID + lane * 2];
        ax += v0.x;
        ay += v0.y;
    }
    float inv = 1.0f / fmaxf((float)(end - beg), 1.0f);
    *(float2*)&out[(size_t)node * HID + lane * 2] = make_float2(ax * inv, ay * inv);
}

// ---------------- f32 GEMM: C[M,128] = A[M,K] @ W[K,128] + b ----------------
// BM=64, BN=128, BK=64; 256 threads; per-thread 8 rows x 4 cols.
// SPLIT: K=256 where k<128 from A0 and k>=128 from A1 (both lda=128) — fused concat.

template <int KTILES, bool SPLIT, bool RELU>
__global__ __launch_bounds__(256) void gemm128(const float* __restrict__ A0,
                                               const float* __restrict__ A1, int lda,
                                               const float* __restrict__ W,
                                               const float* __restrict__ bias,
                                               float* __restrict__ C, int M) {
    __shared__ float As[64 * 64];
    __shared__ float Ws[64 * 128];
    int tid = threadIdx.x;
    int row0 = blockIdx.x * 64;
    int tx = tid & 31;   // col group: cols tx*4 .. tx*4+3
    int ty = tid >> 5;   // row group: rows ty*8 .. ty*8+7

    float acc[8][4];
#pragma unroll
    for (int r = 0; r < 8; ++r)
#pragma unroll
        for (int j = 0; j < 4; ++j) acc[r][j] = 0.f;

#pragma unroll
    for (int kt = 0; kt < KTILES; ++kt) {
        const float* Asrc;
        int kbase;
        if (SPLIT) {
            if (kt < 2) { Asrc = A0; kbase = kt * 64; }
            else        { Asrc = A1; kbase = (kt - 2) * 64; }
        } else {
            Asrc = A0; kbase = kt * 64;
        }
        // stage A tile 64x64
#pragma unroll
        for (int i = 0; i < 4; ++i) {
            int r = i * 16 + (tid >> 4);
            int c = (tid & 15) * 4;
            *(float4*)&As[r * 64 + c] =
                *(const float4*)&Asrc[(size_t)(row0 + r) * lda + kbase + c];
        }
        // stage W tile 64x128
#pragma unroll
        for (int i = 0; i < 8; ++i) {
            int r = i * 8 + (tid >> 5);
            int c = (tid & 31) * 4;
            *(float4*)&Ws[r * 128 + c] = *(const float4*)&W[(size_t)(kt * 64 + r) * 128 + c];
        }
        __syncthreads();
#pragma unroll
        for (int kk = 0; kk < 64; kk += 4) {
            float4 a4[8];
#pragma unroll
            for (int r = 0; r < 8; ++r) a4[r] = *(const float4*)&As[(ty * 8 + r) * 64 + kk];
            float4 w4[4];
#pragma unroll
            for (int i = 0; i < 4; ++i) w4[i] = *(const float4*)&Ws[(kk + i) * 128 + tx * 4];
#pragma unroll
            for (int r = 0; r < 8; ++r) {
#pragma unroll
                for (int i = 0; i < 4; ++i) {
                    float a = ((const float*)&a4[r])[i];
                    acc[r][0] += a * w4[i].x;
                    acc[r][1] += a * w4[i].y;
                    acc[r][2] += a * w4[i].z;
                    acc[r][3] += a * w4[i].w;
                }
            }
        }
        __syncthreads();
    }

    float4 bv = *(const float4*)&bias[tx * 4];
#pragma unroll
    for (int r = 0; r < 8; ++r) {
        float4 o;
        o.x = acc[r][0] + bv.x;
        o.y = acc[r][1] + bv.y;
        o.z = acc[r][2] + bv.z;
        o.w = acc[r][3] + bv.w;
        if (RELU) {
            o.x = fmaxf(o.x, 0.f);
            o.y = fmaxf(o.y, 0.f);
            o.z = fmaxf(o.z, 0.f);
            o.w = fmaxf(o.w, 0.f);
        }
        *(float4*)&C[(size_t)(row0 + ty * 8 + r) * 128 + tx * 4] = o;
    }
}

// ---------------- launch ----------------

extern "C" void kernel_launch(void* const* d_in, const int* in_sizes, int n_in,
                              void* d_out, int out_size, void* d_ws, size_t ws_size,
                              hipStream_t stream) {
    const float* x     = (const float*)d_in[0];
    const float* W_in  = (const float*)d_in[1];
    const float* b_in  = (const float*)d_in[2];
    const float* W_m0  = (const float*)d_in[3];
    const float* b_m0  = (const float*)d_in[4];
    const float* W_m1  = (const float*)d_in[5];
    const float* b_m1  = (const float*)d_in[6];
    const float* W_o   = (const float*)d_in[7];
    const float* b_o   = (const float*)d_in[8];
    const int*   eidx  = (const int*)d_in[9];
    const int* src = eidx;
    const int* dst = eidx + N_EDGES;

    char* ws = (char*)d_ws;
    size_t off = 0;
    auto alloc = [&](size_t bytes) -> char* {
        char* p = ws + off;
        off += (bytes + 255) & ~(size_t)255;
        return p;
    };
    int* deg     = (int*)alloc((size_t)N_NODES * 4);
    int* row_off = (int*)alloc((size_t)(N_NODES + 1) * 4);
    int* cursor  = (int*)alloc((size_t)N_NODES * 4);
    int* csr     = (int*)alloc((size_t)N_EDGES * 4);
    float* hA    = (float*)alloc((size_t)N_NODES * HID * 4);
    float* hB    = (float*)alloc((size_t)N_NODES * HID * 4);
    float* hC    = (float*)alloc((size_t)N_NODES * HID * 4);
    (void)ws_size;

    hipMemsetAsync(deg, 0, (size_t)N_NODES * 4, stream);
    deg_count<<<(N_EDGES + 255) / 256, 256, 0, stream>>>(dst, deg, N_EDGES);
    scan_kernel<<<1, 1024, 0, stream>>>(deg, row_off, cursor, N_NODES);
    scatter_edges<<<(N_EDGES + 255) / 256, 256, 0, stream>>>(src, dst, cursor, csr, N_EDGES);

    // h = relu(x @ W_in + b_in)
    gemm128<4, false, true><<<625, 256, 0, stream>>>(x, nullptr, IN_DIM, W_in, b_in, hA, N_NODES);

    // layer 0
    agg_mean<<<10000, 256, 0, stream>>>(hA, row_off, csr, hB, N_NODES);
    agg_mean<<<10000, 256, 0, stream>>>(hB, row_off, csr, hC, N_NODES);
    gemm128<4, true, true><<<625, 256, 0, stream>>>(hB, hC, HID, W_m0, b_m0, hA, N_NODES);

    // layer 1
    agg_mean<<<10000, 256, 0, stream>>>(hA, row_off, csr, hB, N_NODES);
    agg_mean<<<10000, 256, 0, stream>>>(hB, row_off, csr, hC, N_NODES);
    gemm128<4, true, false><<<625, 256, 0, stream>>>(hB, hC, HID, W_m1, b_m1, hA, N_NODES);

    // out = h @ W_out + b_out
    gemm128<2, false, false><<<625, 256, 0, stream>>>(hA, nullptr, HID, W_o, b_o, (float*)d_out, N_NODES);
}

// Round 2
// 438.462 us; speedup vs baseline: 1.1691x; 1.1691x over previous
//
#include <hip/hip_runtime.h>

#define N_NODES 40000
#define N_EDGES 640000
#define IN_DIM 256
#define HID 128

// ---------------- CSR build ----------------

__global__ void deg_count(const int* __restrict__ dst, int* __restrict__ deg, int E) {
    int e = blockIdx.x * 256 + threadIdx.x;
    if (e < E) atomicAdd(&deg[dst[e]], 1);
}

// Stage 1: per-block sums of deg (1024 elements per block)
__global__ __launch_bounds__(1024) void block_sums(const int* __restrict__ deg,
                                                   int* __restrict__ bsum, int N) {
    __shared__ int sh[1024];
    int tid = threadIdx.x;
    int i = blockIdx.x * 1024 + tid;
    sh[tid] = (i < N) ? deg[i] : 0;
    __syncthreads();
#pragma unroll
    for (int off = 512; off > 0; off >>= 1) {
        if (tid < off) sh[tid] += sh[tid + off];
        __syncthreads();
    }
    if (tid == 0) bsum[blockIdx.x] = sh[0];
}

// Stage 2: exclusive scan of the (<=64) block sums — tiny, serial
__global__ void scan_bsums(int* __restrict__ bsum, int nb) {
    if (threadIdx.x == 0 && blockIdx.x == 0) {
        int run = 0;
        for (int b = 0; b < nb; ++b) {
            int v = bsum[b];
            bsum[b] = run;
            run += v;
        }
    }
}

// Stage 3: block-local exclusive scan + global block offset -> row_off / cursor
__global__ __launch_bounds__(1024) void write_offsets(const int* __restrict__ deg,
                                                      const int* __restrict__ bsum,
                                                      int* __restrict__ row_off,
                                                      int* __restrict__ cursor, int N) {
    __shared__ int sh[1024];
    int tid = threadIdx.x;
    int i = blockIdx.x * 1024 + tid;
    int v = (i < N) ? deg[i] : 0;
    sh[tid] = v;
    __syncthreads();
#pragma unroll
    for (int off = 1; off < 1024; off <<= 1) {
        int t = (tid >= off) ? sh[tid - off] : 0;
        __syncthreads();
        sh[tid] += t;
        __syncthreads();
    }
    int excl = sh[tid] - v + bsum[blockIdx.x];
    if (i < N) {
        row_off[i] = excl;
        cursor[i] = excl;
    }
    if (i == N - 1) row_off[N] = excl + v;
}

__global__ void scatter_edges(const int* __restrict__ src, const int* __restrict__ dst,
                              int* __restrict__ cursor, int* __restrict__ csr, int E) {
    int e = blockIdx.x * 256 + threadIdx.x;
    if (e < E) {
        int p = atomicAdd(&cursor[dst[e]], 1);
        csr[p] = src[e];
    }
}

// ---------------- mean aggregation: one wave per node ----------------

__global__ __launch_bounds__(256) void agg_mean(const float* __restrict__ h,
                                                const int* __restrict__ row_off,
                                                const int* __restrict__ csr,
                                                float* __restrict__ out, int N) {
    int node = blockIdx.x * 4 + (threadIdx.x >> 6);
    if (node >= N) return;
    int lane = threadIdx.x & 63;
    int beg = row_off[node], end = row_off[node + 1];
    float ax = 0.f, ay = 0.f;
    int e = beg;
    for (; e + 1 < end; e += 2) {
        int s0 = csr[e], s1 = csr[e + 1];
        float2 v0 = *(const float2*)&h[(size_t)s0 * HID + lane * 2];
        float2 v1 = *(const float2*)&h[(size_t)s1 * HID + lane * 2];
        ax += v0.x + v1.x;
        ay += v0.y + v1.y;
    }
    if (e < end) {
        int s0 = csr[e];
        float2 v0 = *(const float2*)&h[(size_t)s0 * HID + lane * 2];
        ax += v0.x;
        ay += v0.y;
    }
    float inv = 1.0f / fmaxf((float)(end - beg), 1.0f);
    *(float2*)&out[(size_t)node * HID + lane * 2] = make_float2(ax * inv, ay * inv);
}

// ---------------- f32 GEMM: C[M,128] = A[M,K] @ W[K,128] + b ----------------
// BM=64, BN=128, BK=64; 256 threads; per-thread 8 rows x 4 cols.
// SPLIT: K=256 where k<128 from A0 and k>=128 from A1 (both lda=128) — fused concat.

template <int KTILES, bool SPLIT, bool RELU>
__global__ __launch_bounds__(256) void gemm128(const float* __restrict__ A0,
                                               const float* __restrict__ A1, int lda,
                                               const float* __restrict__ W,
                                               const float* __restrict__ bias,
                                               float* __restrict__ C, int M) {
    __shared__ float As[64 * 64];
    __shared__ float Ws[64 * 128];
    int tid = threadIdx.x;
    int row0 = blockIdx.x * 64;
    int tx = tid & 31;   // col group: cols tx*4 .. tx*4+3
    int ty = tid >> 5;   // row group: rows ty*8 .. ty*8+7

    float acc[8][4];
#pragma unroll
    for (int r = 0; r < 8; ++r)
#pragma unroll
        for (int j = 0; j < 4; ++j) acc[r][j] = 0.f;

#pragma unroll
    for (int kt = 0; kt < KTILES; ++kt) {
        const float* Asrc;
        int kbase;
        if (SPLIT) {
            if (kt < 2) { Asrc = A0; kbase = kt * 64; }
            else        { Asrc = A1; kbase = (kt - 2) * 64; }
        } else {
            Asrc = A0; kbase = kt * 64;
        }
        // stage A tile 64x64
#pragma unroll
        for (int i = 0; i < 4; ++i) {
            int r = i * 16 + (tid >> 4);
            int c = (tid & 15) * 4;
            *(float4*)&As[r * 64 + c] =
                *(const float4*)&Asrc[(size_t)(row0 + r) * lda + kbase + c];
        }
        // stage W tile 64x128
#pragma unroll
        for (int i = 0; i < 8; ++i) {
            int r = i * 8 + (tid >> 5);
            int c = (tid & 31) * 4;
            *(float4*)&Ws[r * 128 + c] = *(const float4*)&W[(size_t)(kt * 64 + r) * 128 + c];
        }
        __syncthreads();
#pragma unroll
        for (int kk = 0; kk < 64; kk += 4) {
            float4 a4[8];
#pragma unroll
            for (int r = 0; r < 8; ++r) a4[r] = *(const float4*)&As[(ty * 8 + r) * 64 + kk];
            float4 w4[4];
#pragma unroll
            for (int i = 0; i < 4; ++i) w4[i] = *(const float4*)&Ws[(kk + i) * 128 + tx * 4];
#pragma unroll
            for (int r = 0; r < 8; ++r) {
#pragma unroll
                for (int i = 0; i < 4; ++i) {
                    float a = ((const float*)&a4[r])[i];
                    acc[r][0] += a * w4[i].x;
                    acc[r][1] += a * w4[i].y;
                    acc[r][2] += a * w4[i].z;
                    acc[r][3] += a * w4[i].w;
                }
            }
        }
        __syncthreads();
    }

    float4 bv = *(const float4*)&bias[tx * 4];
#pragma unroll
    for (int r = 0; r < 8; ++r) {
        float4 o;
        o.x = acc[r][0] + bv.x;
        o.y = acc[r][1] + bv.y;
        o.z = acc[r][2] + bv.z;
        o.w = acc[r][3] + bv.w;
        if (RELU) {
            o.x = fmaxf(o.x, 0.f);
            o.y = fmaxf(o.y, 0.f);
            o.z = fmaxf(o.z, 0.f);
            o.w = fmaxf(o.w, 0.f);
        }
        *(float4*)&C[(size_t)(row0 + ty * 8 + r) * 128 + tx * 4] = o;
    }
}

// ---------------- launch ----------------

extern "C" void kernel_launch(void* const* d_in, const int* in_sizes, int n_in,
                              void* d_out, int out_size, void* d_ws, size_t ws_size,
                              hipStream_t stream) {
    const float* x     = (const float*)d_in[0];
    const float* W_in  = (const float*)d_in[1];
    const float* b_in  = (const float*)d_in[2];
    const float* W_m0  = (const float*)d_in[3];
    const float* b_m0  = (const float*)d_in[4];
    const float* W_m1  = (const float*)d_in[5];
    const float* b_m1  = (const float*)d_in[6];
    const float* W_o   = (const float*)d_in[7];
    const float* b_o   = (const float*)d_in[8];
    const int*   eidx  = (const int*)d_in[9];
    const int* src = eidx;
    const int* dst = eidx + N_EDGES;

    char* ws = (char*)d_ws;
    size_t off = 0;
    auto alloc = [&](size_t bytes) -> char* {
        char* p = ws + off;
        off += (bytes + 255) & ~(size_t)255;
        return p;
    };
    int* deg     = (int*)alloc((size_t)N_NODES * 4);
    int* row_off = (int*)alloc((size_t)(N_NODES + 1) * 4);
    int* cursor  = (int*)alloc((size_t)N_NODES * 4);
    int* csr     = (int*)alloc((size_t)N_EDGES * 4);
    int* bsum    = (int*)alloc(64 * 4);
    float* hA    = (float*)alloc((size_t)N_NODES * HID * 4);
    float* hB    = (float*)alloc((size_t)N_NODES * HID * 4);
    float* hC    = (float*)alloc((size_t)N_NODES * HID * 4);
    (void)ws_size;

    const int NB = (N_NODES + 1023) / 1024;  // 40

    hipMemsetAsync(deg, 0, (size_t)N_NODES * 4, stream);
    deg_count<<<(N_EDGES + 255) / 256, 256, 0, stream>>>(dst, deg, N_EDGES);
    block_sums<<<NB, 1024, 0, stream>>>(deg, bsum, N_NODES);
    scan_bsums<<<1, 64, 0, stream>>>(bsum, NB);
    write_offsets<<<NB, 1024, 0, stream>>>(deg, bsum, row_off, cursor, N_NODES);
    scatter_edges<<<(N_EDGES + 255) / 256, 256, 0, stream>>>(src, dst, cursor, csr, N_EDGES);

    // h = relu(x @ W_in + b_in)
    gemm128<4, false, true><<<625, 256, 0, stream>>>(x, nullptr, IN_DIM, W_in, b_in, hA, N_NODES);

    // layer 0
    agg_mean<<<10000, 256, 0, stream>>>(hA, row_off, csr, hB, N_NODES);
    agg_mean<<<10000, 256, 0, stream>>>(hB, row_off, csr, hC, N_NODES);
    gemm128<4, true, true><<<625, 256, 0, stream>>>(hB, hC, HID, W_m0, b_m0, hA, N_NODES);

    // layer 1
    agg_mean<<<10000, 256, 0, stream>>>(hA, row_off, csr, hB, N_NODES);
    agg_mean<<<10000, 256, 0, stream>>>(hB, row_off, csr, hC, N_NODES);
    gemm128<4, true, false><<<625, 256, 0, stream>>>(hB, hC, HID, W_m1, b_m1, hA, N_NODES);

    // out = h @ W_out + b_out
    gemm128<2, false, false><<<625, 256, 0, stream>>>(hA, nullptr, HID, W_o, b_o, (float*)d_out, N_NODES);
}

// Round 3
// 339.328 us; speedup vs baseline: 1.5106x; 1.2921x over previous
//
#include <hip/hip_runtime.h>

#define N_NODES 40000
#define N_EDGES 640000
#define IN_DIM 256
#define HID 128

typedef short bf16x8 __attribute__((ext_vector_type(8)));
typedef float f32x4 __attribute__((ext_vector_type(4)));

__device__ __forceinline__ unsigned short f2bf(float f) {
    unsigned int u = __float_as_uint(f);
    unsigned int r = (u + 0x7FFFu + ((u >> 16) & 1u)) >> 16;
    return (unsigned short)r;
}
__device__ __forceinline__ float bf2f(unsigned short b) {
    return __uint_as_float(((unsigned int)b) << 16);
}

// ---------------- CSR build ----------------

__global__ void deg_count(const int* __restrict__ dst, int* __restrict__ deg, int E) {
    int e = blockIdx.x * 256 + threadIdx.x;
    if (e < E) atomicAdd(&deg[dst[e]], 1);
}

__global__ __launch_bounds__(1024) void block_sums(const int* __restrict__ deg,
                                                   int* __restrict__ bsum, int N) {
    __shared__ int sh[1024];
    int tid = threadIdx.x;
    int i = blockIdx.x * 1024 + tid;
    sh[tid] = (i < N) ? deg[i] : 0;
    __syncthreads();
#pragma unroll
    for (int off = 512; off > 0; off >>= 1) {
        if (tid < off) sh[tid] += sh[tid + off];
        __syncthreads();
    }
    if (tid == 0) bsum[blockIdx.x] = sh[0];
}

__global__ void scan_bsums(int* __restrict__ bsum, int nb) {
    if (threadIdx.x == 0 && blockIdx.x == 0) {
        int run = 0;
        for (int b = 0; b < nb; ++b) {
            int v = bsum[b];
            bsum[b] = run;
            run += v;
        }
    }
}

__global__ __launch_bounds__(1024) void write_offsets(const int* __restrict__ deg,
                                                      const int* __restrict__ bsum,
                                                      int* __restrict__ row_off,
                                                      int* __restrict__ cursor, int N) {
    __shared__ int sh[1024];
    int tid = threadIdx.x;
    int i = blockIdx.x * 1024 + tid;
    int v = (i < N) ? deg[i] : 0;
    sh[tid] = v;
    __syncthreads();
#pragma unroll
    for (int off = 1; off < 1024; off <<= 1) {
        int t = (tid >= off) ? sh[tid - off] : 0;
        __syncthreads();
        sh[tid] += t;
        __syncthreads();
    }
    int excl = sh[tid] - v + bsum[blockIdx.x];
    if (i < N) {
        row_off[i] = excl;
        cursor[i] = excl;
    }
    if (i == N - 1) row_off[N] = excl + v;
}

__global__ void scatter_edges(const int* __restrict__ src, const int* __restrict__ dst,
                              int* __restrict__ cursor, int* __restrict__ csr, int E) {
    int e = blockIdx.x * 256 + threadIdx.x;
    if (e < E) {
        int p = atomicAdd(&cursor[dst[e]], 1);
        csr[p] = src[e];
    }
}

// ---------------- mean aggregation: one wave per node ----------------

__global__ __launch_bounds__(256) void agg_mean(const float* __restrict__ h,
                                                const int* __restrict__ row_off,
                                                const int* __restrict__ csr,
                                                float* __restrict__ out, int N) {
    int node = blockIdx.x * 4 + (threadIdx.x >> 6);
    if (node >= N) return;
    int lane = threadIdx.x & 63;
    int beg = row_off[node], end = row_off[node + 1];
    float ax = 0.f, ay = 0.f;
    int e = beg;
    for (; e + 1 < end; e += 2) {
        int s0 = csr[e], s1 = csr[e + 1];
        float2 v0 = *(const float2*)&h[(size_t)s0 * HID + lane * 2];
        float2 v1 = *(const float2*)&h[(size_t)s1 * HID + lane * 2];
        ax += v0.x + v1.x;
        ay += v0.y + v1.y;
    }
    if (e < end) {
        int s0 = csr[e];
        float2 v0 = *(const float2*)&h[(size_t)s0 * HID + lane * 2];
        ax += v0.x;
        ay += v0.y;
    }
    float inv = 1.0f / fmaxf((float)(end - beg), 1.0f);
    *(float2*)&out[(size_t)node * HID + lane * 2] = make_float2(ax * inv, ay * inv);
}

// ---------------- W prep: f32 [K][128] -> tiled transposed bf16 hi/lo ----------------
// dest[s][c][k'] (s = k>>5, k' = k&31): B-frag reads become lane-contiguous.

__global__ __launch_bounds__(256) void prep_all(
    const float* __restrict__ W0, const float* __restrict__ W1,
    const float* __restrict__ W2, const float* __restrict__ W3,
    unsigned short* __restrict__ H0, unsigned short* __restrict__ L0,
    unsigned short* __restrict__ H1, unsigned short* __restrict__ L1,
    unsigned short* __restrict__ H2, unsigned short* __restrict__ L2,
    unsigned short* __restrict__ H3, unsigned short* __restrict__ L3) {
    int i = blockIdx.x * 256 + threadIdx.x;
    const float* W;
    unsigned short *H, *L;
    int local;
    if (i < 32768)       { W = W0; H = H0; L = L0; local = i; }
    else if (i < 65536)  { W = W1; H = H1; L = L1; local = i - 32768; }
    else if (i < 98304)  { W = W2; H = H2; L = L2; local = i - 65536; }
    else if (i < 114688) { W = W3; H = H3; L = L3; local = i - 98304; }
    else return;
    int k = local >> 7, c = local & 127;
    float w = W[local];
    unsigned short h = f2bf(w);
    unsigned short l = f2bf(w - bf2f(h));
    int d = (k >> 5) * 4096 + c * 32 + (k & 31);
    H[d] = h;
    L[d] = l;
}

// ---------------- split-bf16 MFMA GEMM: C[M,128] = A[M,K] @ W[K,128] + b ----------------
// BM=64 (625 blocks exact), BN=128, BK=32. 4 waves 2x2, wave = 32x64 = 2x4 frags 16x16.
// a*b ~= a_hi*b_hi + a_hi*b_lo + a_lo*b_hi  (3 MFMAs, fp32-like precision).

template <int KSTEPS, bool SPLIT, bool RELU>
__global__ __launch_bounds__(256) void gemm_mfma(
    const float* __restrict__ A0, const float* __restrict__ A1, int lda,
    const unsigned short* __restrict__ Bth, const unsigned short* __restrict__ Btl,
    const float* __restrict__ bias, float* __restrict__ C) {
    __shared__ unsigned short Ah[64 * 32], Al[64 * 32];
    __shared__ unsigned short Bh[128 * 32], Bl[128 * 32];
    int tid = threadIdx.x;
    int lane = tid & 63, wid = tid >> 6;
    int wr = wid >> 1, wc = wid & 1;
    int row0 = blockIdx.x * 64;

    f32x4 acc[2][4];
#pragma unroll
    for (int rt = 0; rt < 2; ++rt)
#pragma unroll
        for (int ct = 0; ct < 4; ++ct) acc[rt][ct] = 0.f;

    for (int s = 0; s < KSTEPS; ++s) {
        const float* Asrc = (!SPLIT || s < KSTEPS / 2) ? A0 : A1;
        int kbase = SPLIT ? (s & (KSTEPS / 2 - 1)) * 32 : s * 32;

        // stage A 64x32 f32 -> hi/lo bf16 (512 float4 chunks, 2 per thread)
#pragma unroll
        for (int i = 0; i < 2; ++i) {
            int cch = tid + i * 256;
            int r = cch >> 3, q = cch & 7;
            float4 v = *(const float4*)&Asrc[(size_t)(row0 + r) * lda + kbase + q * 4];
            ushort4 hh, ll;
            hh.x = f2bf(v.x); ll.x = f2bf(v.x - bf2f(hh.x));
            hh.y = f2bf(v.y); ll.y = f2bf(v.y - bf2f(hh.y));
            hh.z = f2bf(v.z); ll.z = f2bf(v.z - bf2f(hh.z));
            hh.w = f2bf(v.w); ll.w = f2bf(v.w - bf2f(hh.w));
            *(ushort4*)&Ah[r * 32 + q * 4] = hh;
            *(ushort4*)&Al[r * 32 + q * 4] = ll;
        }
        // stage B: contiguous 8KB copy per plane (pre-tiled/transposed)
        {
            const float4* sh4 = (const float4*)(Bth + s * 4096);
            const float4* sl4 = (const float4*)(Btl + s * 4096);
            float4* dh4 = (float4*)Bh;
            float4* dl4 = (float4*)Bl;
            dh4[tid] = sh4[tid];
            dh4[tid + 256] = sh4[tid + 256];
            dl4[tid] = sl4[tid];
            dl4[tid + 256] = sl4[tid + 256];
        }
        __syncthreads();

        bf16x8 afh[2], afl[2], bfh[4], bfl[4];
#pragma unroll
        for (int rt = 0; rt < 2; ++rt) {
            int off = (wr * 32 + rt * 16 + (lane & 15)) * 32 + (lane >> 4) * 8;
            afh[rt] = *(const bf16x8*)&Ah[off];
            afl[rt] = *(const bf16x8*)&Al[off];
        }
#pragma unroll
        for (int ct = 0; ct < 4; ++ct) {
            int off = (wc * 64 + ct * 16 + (lane & 15)) * 32 + (lane >> 4) * 8;
            bfh[ct] = *(const bf16x8*)&Bh[off];
            bfl[ct] = *(const bf16x8*)&Bl[off];
        }
#pragma unroll
        for (int rt = 0; rt < 2; ++rt)
#pragma unroll
            for (int ct = 0; ct < 4; ++ct) {
                acc[rt][ct] = __builtin_amdgcn_mfma_f32_16x16x32_bf16(afh[rt], bfh[ct], acc[rt][ct], 0, 0, 0);
                acc[rt][ct] = __builtin_amdgcn_mfma_f32_16x16x32_bf16(afh[rt], bfl[ct], acc[rt][ct], 0, 0, 0);
                acc[rt][ct] = __builtin_amdgcn_mfma_f32_16x16x32_bf16(afl[rt], bfh[ct], acc[rt][ct], 0, 0, 0);
            }
        __syncthreads();
    }

    // epilogue: D[row=(lane>>4)*4+reg][col=lane&15] per 16x16 frag
#pragma unroll
    for (int ct = 0; ct < 4; ++ct) {
        int col = wc * 64 + ct * 16 + (lane & 15);
        float bv = bias[col];
#pragma unroll
        for (int rt = 0; rt < 2; ++rt) {
#pragma unroll
            for (int r = 0; r < 4; ++r) {
                int row = row0 + wr * 32 + rt * 16 + (lane >> 4) * 4 + r;
                float v = acc[rt][ct][r] + bv;
                if (RELU) v = fmaxf(v, 0.f);
                C[(size_t)row * 128 + col] = v;
            }
        }
    }
}

// ---------------- launch ----------------

extern "C" void kernel_launch(void* const* d_in, const int* in_sizes, int n_in,
                              void* d_out, int out_size, void* d_ws, size_t ws_size,
                              hipStream_t stream) {
    const float* x     = (const float*)d_in[0];
    const float* W_in  = (const float*)d_in[1];
    const float* b_in  = (const float*)d_in[2];
    const float* W_m0  = (const float*)d_in[3];
    const float* b_m0  = (const float*)d_in[4];
    const float* W_m1  = (const float*)d_in[5];
    const float* b_m1  = (const float*)d_in[6];
    const float* W_o   = (const float*)d_in[7];
    const float* b_o   = (const float*)d_in[8];
    const int*   eidx  = (const int*)d_in[9];
    const int* src = eidx;
    const int* dst = eidx + N_EDGES;

    char* ws = (char*)d_ws;
    size_t off = 0;
    auto alloc = [&](size_t bytes) -> char* {
        char* p = ws + off;
        off += (bytes + 255) & ~(size_t)255;
        return p;
    };
    int* deg     = (int*)alloc((size_t)N_NODES * 4);
    int* row_off = (int*)alloc((size_t)(N_NODES + 1) * 4);
    int* cursor  = (int*)alloc((size_t)N_NODES * 4);
    int* csr     = (int*)alloc((size_t)N_EDGES * 4);
    int* bsum    = (int*)alloc(64 * 4);
    float* hA    = (float*)alloc((size_t)N_NODES * HID * 4);
    float* hB    = (float*)alloc((size_t)N_NODES * HID * 4);
    float* hC    = (float*)alloc((size_t)N_NODES * HID * 4);
    unsigned short* WinH = (unsigned short*)alloc(32768 * 2);
    unsigned short* WinL = (unsigned short*)alloc(32768 * 2);
    unsigned short* Wm0H = (unsigned short*)alloc(32768 * 2);
    unsigned short* Wm0L = (unsigned short*)alloc(32768 * 2);
    unsigned short* Wm1H = (unsigned short*)alloc(32768 * 2);
    unsigned short* Wm1L = (unsigned short*)alloc(32768 * 2);
    unsigned short* WoH  = (unsigned short*)alloc(16384 * 2);
    unsigned short* WoL  = (unsigned short*)alloc(16384 * 2);
    (void)ws_size;

    const int NB = (N_NODES + 1023) / 1024;  // 40

    hipMemsetAsync(deg, 0, (size_t)N_NODES * 4, stream);
    deg_count<<<(N_EDGES + 255) / 256, 256, 0, stream>>>(dst, deg, N_EDGES);
    block_sums<<<NB, 1024, 0, stream>>>(deg, bsum, N_NODES);
    scan_bsums<<<1, 64, 0, stream>>>(bsum, NB);
    write_offsets<<<NB, 1024, 0, stream>>>(deg, bsum, row_off, cursor, N_NODES);
    scatter_edges<<<(N_EDGES + 255) / 256, 256, 0, stream>>>(src, dst, cursor, csr, N_EDGES);

    prep_all<<<448, 256, 0, stream>>>(W_in, W_m0, W_m1, W_o,
                                      WinH, WinL, Wm0H, Wm0L, Wm1H, Wm1L, WoH, WoL);

    // h = relu(x @ W_in + b_in)
    gemm_mfma<8, false, true><<<625, 256, 0, stream>>>(x, nullptr, IN_DIM, WinH, WinL, b_in, hA);

    // layer 0
    agg_mean<<<10000, 256, 0, stream>>>(hA, row_off, csr, hB, N_NODES);
    agg_mean<<<10000, 256, 0, stream>>>(hB, row_off, csr, hC, N_NODES);
    gemm_mfma<8, true, true><<<625, 256, 0, stream>>>(hB, hC, HID, Wm0H, Wm0L, b_m0, hA);

    // layer 1
    agg_mean<<<10000, 256, 0, stream>>>(hA, row_off, csr, hB, N_NODES);
    agg_mean<<<10000, 256, 0, stream>>>(hB, row_off, csr, hC, N_NODES);
    gemm_mfma<8, true, false><<<625, 256, 0, stream>>>(hB, hC, HID, Wm1H, Wm1L, b_m1, hA);

    // out = h @ W_out + b_out
    gemm_mfma<4, false, false><<<625, 256, 0, stream>>>(hA, nullptr, HID, WoH, WoL, b_o, (float*)d_out);
}

// Round 4
// 311.554 us; speedup vs baseline: 1.6453x; 1.0891x over previous
//
#include <hip/hip_runtime.h>

#define N_NODES 40000
#define N_EDGES 640000
#define IN_DIM 256
#define HID 128

typedef short bf16x8 __attribute__((ext_vector_type(8)));
typedef float f32x4 __attribute__((ext_vector_type(4)));

__device__ __forceinline__ unsigned short f2bf(float f) {
    unsigned int u = __float_as_uint(f);
    unsigned int r = (u + 0x7FFFu + ((u >> 16) & 1u)) >> 16;
    return (unsigned short)r;
}
__device__ __forceinline__ float bf2f(unsigned short b) {
    return __uint_as_float(((unsigned int)b) << 16);
}

// ---------------- CSR build ----------------

__global__ void deg_count(const int* __restrict__ dst, int* __restrict__ deg, int E) {
    int e = blockIdx.x * 256 + threadIdx.x;
    if (e < E) atomicAdd(&deg[dst[e]], 1);
}

__global__ __launch_bounds__(1024) void block_sums(const int* __restrict__ deg,
                                                   int* __restrict__ bsum, int N) {
    __shared__ int sh[1024];
    int tid = threadIdx.x;
    int i = blockIdx.x * 1024 + tid;
    sh[tid] = (i < N) ? deg[i] : 0;
    __syncthreads();
#pragma unroll
    for (int off = 512; off > 0; off >>= 1) {
        if (tid < off) sh[tid] += sh[tid + off];
        __syncthreads();
    }
    if (tid == 0) bsum[blockIdx.x] = sh[0];
}

__global__ void scan_bsums(int* __restrict__ bsum, int nb) {
    if (threadIdx.x == 0 && blockIdx.x == 0) {
        int run = 0;
        for (int b = 0; b < nb; ++b) {
            int v = bsum[b];
            bsum[b] = run;
            run += v;
        }
    }
}

__global__ __launch_bounds__(1024) void write_offsets(const int* __restrict__ deg,
                                                      const int* __restrict__ bsum,
                                                      int* __restrict__ row_off,
                                                      int* __restrict__ cursor, int N) {
    __shared__ int sh[1024];
    int tid = threadIdx.x;
    int i = blockIdx.x * 1024 + tid;
    int v = (i < N) ? deg[i] : 0;
    sh[tid] = v;
    __syncthreads();
#pragma unroll
    for (int off = 1; off < 1024; off <<= 1) {
        int t = (tid >= off) ? sh[tid - off] : 0;
        __syncthreads();
        sh[tid] += t;
        __syncthreads();
    }
    int excl = sh[tid] - v + bsum[blockIdx.x];
    if (i < N) {
        row_off[i] = excl;
        cursor[i] = excl;
    }
    if (i == N - 1) row_off[N] = excl + v;
}

__global__ void scatter_edges(const int* __restrict__ src, const int* __restrict__ dst,
                              int* __restrict__ cursor, int* __restrict__ csr, int E) {
    int e = blockIdx.x * 256 + threadIdx.x;
    if (e < E) {
        int p = atomicAdd(&cursor[dst[e]], 1);
        csr[p] = src[e];
    }
}

// ---------------- mean aggregation ----------------
// One wave per node. Lane halves process alternating edges; float4 per lane.
// 4 independent 512B row-loads in flight per wave (2 halves x unroll 2).

__global__ __launch_bounds__(256) void agg_mean(const float* __restrict__ h,
                                                const int* __restrict__ row_off,
                                                const int* __restrict__ csr,
                                                float* __restrict__ out, int N) {
    int node = blockIdx.x * 4 + (threadIdx.x >> 6);
    if (node >= N) return;
    int lane = threadIdx.x & 63;
    int half = lane >> 5;  // 0/1 -> alternating edges
    int sub = lane & 31;   // dim group: dims sub*4 .. sub*4+3
    int beg = row_off[node], end = row_off[node + 1];
    float4 acc = make_float4(0.f, 0.f, 0.f, 0.f);
    int e = beg;
    for (; e + 3 < end; e += 4) {
        int s0 = csr[e + half];
        int s1 = csr[e + 2 + half];
        float4 v0 = *(const float4*)&h[(size_t)s0 * HID + sub * 4];
        float4 v1 = *(const float4*)&h[(size_t)s1 * HID + sub * 4];
        acc.x += v0.x + v1.x;
        acc.y += v0.y + v1.y;
        acc.z += v0.z + v1.z;
        acc.w += v0.w + v1.w;
    }
    for (; e + half < end; e += 2) {
        int s = csr[e + half];
        float4 v = *(const float4*)&h[(size_t)s * HID + sub * 4];
        acc.x += v.x;
        acc.y += v.y;
        acc.z += v.z;
        acc.w += v.w;
    }
    acc.x += __shfl_xor(acc.x, 32);
    acc.y += __shfl_xor(acc.y, 32);
    acc.z += __shfl_xor(acc.z, 32);
    acc.w += __shfl_xor(acc.w, 32);
    if (half == 0) {
        float inv = 1.0f / fmaxf((float)(end - beg), 1.0f);
        acc.x *= inv;
        acc.y *= inv;
        acc.z *= inv;
        acc.w *= inv;
        *(float4*)&out[(size_t)node * HID + sub * 4] = acc;
    }
}

// ---------------- W prep: f32 [K][128] -> tiled transposed bf16 hi/lo ----------------
// dest[s][c][k'] (s = k>>5, k' = k&31): B-frag reads become lane-contiguous.

__global__ __launch_bounds__(256) void prep_all(
    const float* __restrict__ W0, const float* __restrict__ W1,
    const float* __restrict__ W2, const float* __restrict__ W3,
    unsigned short* __restrict__ H0, unsigned short* __restrict__ L0,
    unsigned short* __restrict__ H1, unsigned short* __restrict__ L1,
    unsigned short* __restrict__ H2, unsigned short* __restrict__ L2,
    unsigned short* __restrict__ H3, unsigned short* __restrict__ L3) {
    int i = blockIdx.x * 256 + threadIdx.x;
    const float* W;
    unsigned short *H, *L;
    int local;
    if (i < 32768)       { W = W0; H = H0; L = L0; local = i; }
    else if (i < 65536)  { W = W1; H = H1; L = L1; local = i - 32768; }
    else if (i < 98304)  { W = W2; H = H2; L = L2; local = i - 65536; }
    else if (i < 114688) { W = W3; H = H3; L = L3; local = i - 98304; }
    else return;
    int k = local >> 7, c = local & 127;
    float w = W[local];
    unsigned short h = f2bf(w);
    unsigned short l = f2bf(w - bf2f(h));
    int d = (k >> 5) * 4096 + c * 32 + (k & 31);
    H[d] = h;
    L[d] = l;
}

// ---------------- split-bf16 MFMA GEMM: C[M,128] = A[M,K] @ W[K,128] + b ----------------
// BM=64 (625 blocks exact), BN=128, BK=32. 4 waves 2x2, wave = 32x64 = 2x4 frags 16x16.
// a*b ~= a_hi*b_hi + a_hi*b_lo + a_lo*b_hi  (3 MFMAs, fp32-like precision).

template <int KSTEPS, bool SPLIT, bool RELU>
__global__ __launch_bounds__(256) void gemm_mfma(
    const float* __restrict__ A0, const float* __restrict__ A1, int lda,
    const unsigned short* __restrict__ Bth, const unsigned short* __restrict__ Btl,
    const float* __restrict__ bias, float* __restrict__ C) {
    __shared__ unsigned short Ah[64 * 32], Al[64 * 32];
    __shared__ unsigned short Bh[128 * 32], Bl[128 * 32];
    int tid = threadIdx.x;
    int lane = tid & 63, wid = tid >> 6;
    int wr = wid >> 1, wc = wid & 1;
    int row0 = blockIdx.x * 64;

    f32x4 acc[2][4];
#pragma unroll
    for (int rt = 0; rt < 2; ++rt)
#pragma unroll
        for (int ct = 0; ct < 4; ++ct) acc[rt][ct] = 0.f;

    for (int s = 0; s < KSTEPS; ++s) {
        const float* Asrc = (!SPLIT || s < KSTEPS / 2) ? A0 : A1;
        int kbase = SPLIT ? (s & (KSTEPS / 2 - 1)) * 32 : s * 32;

        // stage A 64x32 f32 -> hi/lo bf16 (512 float4 chunks, 2 per thread)
#pragma unroll
        for (int i = 0; i < 2; ++i) {
            int cch = tid + i * 256;
            int r = cch >> 3, q = cch & 7;
            float4 v = *(const float4*)&Asrc[(size_t)(row0 + r) * lda + kbase + q * 4];
            ushort4 hh, ll;
            hh.x = f2bf(v.x); ll.x = f2bf(v.x - bf2f(hh.x));
            hh.y = f2bf(v.y); ll.y = f2bf(v.y - bf2f(hh.y));
            hh.z = f2bf(v.z); ll.z = f2bf(v.z - bf2f(hh.z));
            hh.w = f2bf(v.w); ll.w = f2bf(v.w - bf2f(hh.w));
            *(ushort4*)&Ah[r * 32 + q * 4] = hh;
            *(ushort4*)&Al[r * 32 + q * 4] = ll;
        }
        // stage B: contiguous 8KB copy per plane (pre-tiled/transposed)
        {
            const float4* sh4 = (const float4*)(Bth + s * 4096);
            const float4* sl4 = (const float4*)(Btl + s * 4096);
            float4* dh4 = (float4*)Bh;
            float4* dl4 = (float4*)Bl;
            dh4[tid] = sh4[tid];
            dh4[tid + 256] = sh4[tid + 256];
            dl4[tid] = sl4[tid];
            dl4[tid + 256] = sl4[tid + 256];
        }
        __syncthreads();

        bf16x8 afh[2], afl[2], bfh[4], bfl[4];
#pragma unroll
        for (int rt = 0; rt < 2; ++rt) {
            int off = (wr * 32 + rt * 16 + (lane & 15)) * 32 + (lane >> 4) * 8;
            afh[rt] = *(const bf16x8*)&Ah[off];
            afl[rt] = *(const bf16x8*)&Al[off];
        }
#pragma unroll
        for (int ct = 0; ct < 4; ++ct) {
            int off = (wc * 64 + ct * 16 + (lane & 15)) * 32 + (lane >> 4) * 8;
            bfh[ct] = *(const bf16x8*)&Bh[off];
            bfl[ct] = *(const bf16x8*)&Bl[off];
        }
#pragma unroll
        for (int rt = 0; rt < 2; ++rt)
#pragma unroll
            for (int ct = 0; ct < 4; ++ct) {
                acc[rt][ct] = __builtin_amdgcn_mfma_f32_16x16x32_bf16(afh[rt], bfh[ct], acc[rt][ct], 0, 0, 0);
                acc[rt][ct] = __builtin_amdgcn_mfma_f32_16x16x32_bf16(afh[rt], bfl[ct], acc[rt][ct], 0, 0, 0);
                acc[rt][ct] = __builtin_amdgcn_mfma_f32_16x16x32_bf16(afl[rt], bfh[ct], acc[rt][ct], 0, 0, 0);
            }
        __syncthreads();
    }

    // epilogue: D[row=(lane>>4)*4+reg][col=lane&15] per 16x16 frag
#pragma unroll
    for (int ct = 0; ct < 4; ++ct) {
        int col = wc * 64 + ct * 16 + (lane & 15);
        float bv = bias[col];
#pragma unroll
        for (int rt = 0; rt < 2; ++rt) {
#pragma unroll
            for (int r = 0; r < 4; ++r) {
                int row = row0 + wr * 32 + rt * 16 + (lane >> 4) * 4 + r;
                float v = acc[rt][ct][r] + bv;
                if (RELU) v = fmaxf(v, 0.f);
                C[(size_t)row * 128 + col] = v;
            }
        }
    }
}

// ---------------- launch ----------------

extern "C" void kernel_launch(void* const* d_in, const int* in_sizes, int n_in,
                              void* d_out, int out_size, void* d_ws, size_t ws_size,
                              hipStream_t stream) {
    const float* x     = (const float*)d_in[0];
    const float* W_in  = (const float*)d_in[1];
    const float* b_in  = (const float*)d_in[2];
    const float* W_m0  = (const float*)d_in[3];
    const float* b_m0  = (const float*)d_in[4];
    const float* W_m1  = (const float*)d_in[5];
    const float* b_m1  = (const float*)d_in[6];
    const float* W_o   = (const float*)d_in[7];
    const float* b_o   = (const float*)d_in[8];
    const int*   eidx  = (const int*)d_in[9];
    const int* src = eidx;
    const int* dst = eidx + N_EDGES;

    char* ws = (char*)d_ws;
    size_t off = 0;
    auto alloc = [&](size_t bytes) -> char* {
        char* p = ws + off;
        off += (bytes + 255) & ~(size_t)255;
        return p;
    };
    int* deg     = (int*)alloc((size_t)N_NODES * 4);
    int* row_off = (int*)alloc((size_t)(N_NODES + 1) * 4);
    int* cursor  = (int*)alloc((size_t)N_NODES * 4);
    int* csr     = (int*)alloc((size_t)N_EDGES * 4);
    int* bsum    = (int*)alloc(64 * 4);
    float* hA    = (float*)alloc((size_t)N_NODES * HID * 4);
    float* hB    = (float*)alloc((size_t)N_NODES * HID * 4);
    float* hC    = (float*)alloc((size_t)N_NODES * HID * 4);
    unsigned short* WinH = (unsigned short*)alloc(32768 * 2);
    unsigned short* WinL = (unsigned short*)alloc(32768 * 2);
    unsigned short* Wm0H = (unsigned short*)alloc(32768 * 2);
    unsigned short* Wm0L = (unsigned short*)alloc(32768 * 2);
    unsigned short* Wm1H = (unsigned short*)alloc(32768 * 2);
    unsigned short* Wm1L = (unsigned short*)alloc(32768 * 2);
    unsigned short* WoH  = (unsigned short*)alloc(16384 * 2);
    unsigned short* WoL  = (unsigned short*)alloc(16384 * 2);
    (void)ws_size;

    const int NB = (N_NODES + 1023) / 1024;  // 40

    hipMemsetAsync(deg, 0, (size_t)N_NODES * 4, stream);
    deg_count<<<(N_EDGES + 255) / 256, 256, 0, stream>>>(dst, deg, N_EDGES);
    block_sums<<<NB, 1024, 0, stream>>>(deg, bsum, N_NODES);
    scan_bsums<<<1, 64, 0, stream>>>(bsum, NB);
    write_offsets<<<NB, 1024, 0, stream>>>(deg, bsum, row_off, cursor, N_NODES);
    scatter_edges<<<(N_EDGES + 255) / 256, 256, 0, stream>>>(src, dst, cursor, csr, N_EDGES);

    prep_all<<<448, 256, 0, stream>>>(W_in, W_m0, W_m1, W_o,
                                      WinH, WinL, Wm0H, Wm0L, Wm1H, Wm1L, WoH, WoL);

    // h = relu(x @ W_in + b_in)
    gemm_mfma<8, false, true><<<625, 256, 0, stream>>>(x, nullptr, IN_DIM, WinH, WinL, b_in, hA);

    // layer 0
    agg_mean<<<10000, 256, 0, stream>>>(hA, row_off, csr, hB, N_NODES);
    agg_mean<<<10000, 256, 0, stream>>>(hB, row_off, csr, hC, N_NODES);
    gemm_mfma<8, true, true><<<625, 256, 0, stream>>>(hB, hC, HID, Wm0H, Wm0L, b_m0, hA);

    // layer 1
    agg_mean<<<10000, 256, 0, stream>>>(hA, row_off, csr, hB, N_NODES);
    agg_mean<<<10000, 256, 0, stream>>>(hB, row_off, csr, hC, N_NODES);
    gemm_mfma<8, true, false><<<625, 256, 0, stream>>>(hB, hC, HID, Wm1H, Wm1L, b_m1, hA);

    // out = h @ W_out + b_out
    gemm_mfma<4, false, false><<<625, 256, 0, stream>>>(hA, nullptr, HID, WoH, WoL, b_o, (float*)d_out);
}

// Round 5
// 310.451 us; speedup vs baseline: 1.6511x; 1.0036x over previous
//
#include <hip/hip_runtime.h>

#define N_NODES 40000
#define N_EDGES 640000
#define IN_DIM 256
#define HID 128

typedef short bf16x8 __attribute__((ext_vector_type(8)));
typedef float f32x4 __attribute__((ext_vector_type(4)));

__device__ __forceinline__ unsigned short f2bf(float f) {
    unsigned int u = __float_as_uint(f);
    unsigned int r = (u + 0x7FFFu + ((u >> 16) & 1u)) >> 16;
    return (unsigned short)r;
}
__device__ __forceinline__ float bf2f(unsigned short b) {
    return __uint_as_float(((unsigned int)b) << 16);
}

// ---------------- CSR build ----------------

__global__ void deg_count(const int* __restrict__ dst, int* __restrict__ deg, int E) {
    int e = blockIdx.x * 256 + threadIdx.x;
    if (e < E) atomicAdd(&deg[dst[e]], 1);
}

__global__ __launch_bounds__(1024) void block_sums(const int* __restrict__ deg,
                                                   int* __restrict__ bsum, int N) {
    __shared__ int sh[1024];
    int tid = threadIdx.x;
    int i = blockIdx.x * 1024 + tid;
    sh[tid] = (i < N) ? deg[i] : 0;
    __syncthreads();
#pragma unroll
    for (int off = 512; off > 0; off >>= 1) {
        if (tid < off) sh[tid] += sh[tid + off];
        __syncthreads();
    }
    if (tid == 0) bsum[blockIdx.x] = sh[0];
}

__global__ void scan_bsums(int* __restrict__ bsum, int nb) {
    if (threadIdx.x == 0 && blockIdx.x == 0) {
        int run = 0;
        for (int b = 0; b < nb; ++b) {
            int v = bsum[b];
            bsum[b] = run;
            run += v;
        }
    }
}

__global__ __launch_bounds__(1024) void write_offsets(const int* __restrict__ deg,
                                                      const int* __restrict__ bsum,
                                                      int* __restrict__ row_off,
                                                      int* __restrict__ cursor, int N) {
    __shared__ int sh[1024];
    int tid = threadIdx.x;
    int i = blockIdx.x * 1024 + tid;
    int v = (i < N) ? deg[i] : 0;
    sh[tid] = v;
    __syncthreads();
#pragma unroll
    for (int off = 1; off < 1024; off <<= 1) {
        int t = (tid >= off) ? sh[tid - off] : 0;
        __syncthreads();
        sh[tid] += t;
        __syncthreads();
    }
    int excl = sh[tid] - v + bsum[blockIdx.x];
    if (i < N) {
        row_off[i] = excl;
        cursor[i] = excl;
    }
    if (i == N - 1) row_off[N] = excl + v;
}

__global__ void scatter_edges(const int* __restrict__ src, const int* __restrict__ dst,
                              int* __restrict__ cursor, int* __restrict__ csr, int E) {
    int e = blockIdx.x * 256 + threadIdx.x;
    if (e < E) {
        int p = atomicAdd(&cursor[dst[e]], 1);
        csr[p] = src[e];
    }
}

// ---------------- mean aggregation ----------------
// One wave per node. Lane halves take alternating edges; float4 per lane.
// Unroll 8 edges/iter -> 4 independent 512B rows in flight per lane-half.

__global__ __launch_bounds__(256) void agg_mean(const float* __restrict__ h,
                                                const int* __restrict__ row_off,
                                                const int* __restrict__ csr,
                                                float* __restrict__ out, int N) {
    int node = blockIdx.x * 4 + (threadIdx.x >> 6);
    if (node >= N) return;
    int lane = threadIdx.x & 63;
    int half = lane >> 5;  // 0/1 -> alternating edges
    int sub = lane & 31;   // dim group: dims sub*4 .. sub*4+3
    int beg = row_off[node], end = row_off[node + 1];
    float4 a0 = make_float4(0.f, 0.f, 0.f, 0.f);
    float4 a1 = make_float4(0.f, 0.f, 0.f, 0.f);
    int e = beg;
    for (; e + 7 < end; e += 8) {
        int s0 = csr[e + half];
        int s1 = csr[e + 2 + half];
        int s2 = csr[e + 4 + half];
        int s3 = csr[e + 6 + half];
        float4 v0 = *(const float4*)&h[(size_t)s0 * HID + sub * 4];
        float4 v1 = *(const float4*)&h[(size_t)s1 * HID + sub * 4];
        float4 v2 = *(const float4*)&h[(size_t)s2 * HID + sub * 4];
        float4 v3 = *(const float4*)&h[(size_t)s3 * HID + sub * 4];
        a0.x += v0.x + v2.x;
        a0.y += v0.y + v2.y;
        a0.z += v0.z + v2.z;
        a0.w += v0.w + v2.w;
        a1.x += v1.x + v3.x;
        a1.y += v1.y + v3.y;
        a1.z += v1.z + v3.z;
        a1.w += v1.w + v3.w;
    }
    for (; e + half < end; e += 2) {
        int s = csr[e + half];
        float4 v = *(const float4*)&h[(size_t)s * HID + sub * 4];
        a0.x += v.x;
        a0.y += v.y;
        a0.z += v.z;
        a0.w += v.w;
    }
    float4 acc;
    acc.x = a0.x + a1.x;
    acc.y = a0.y + a1.y;
    acc.z = a0.z + a1.z;
    acc.w = a0.w + a1.w;
    acc.x += __shfl_xor(acc.x, 32);
    acc.y += __shfl_xor(acc.y, 32);
    acc.z += __shfl_xor(acc.z, 32);
    acc.w += __shfl_xor(acc.w, 32);
    if (half == 0) {
        float inv = 1.0f / fmaxf((float)(end - beg), 1.0f);
        acc.x *= inv;
        acc.y *= inv;
        acc.z *= inv;
        acc.w *= inv;
        *(float4*)&out[(size_t)node * HID + sub * 4] = acc;
    }
}

// ---------------- W prep: f32 [K][128] -> tiled transposed bf16 hi/lo ----------------
// dest[s][c][k'] (s = k>>5, k' = k&31): B-frag reads become lane-contiguous.

__global__ __launch_bounds__(256) void prep_all(
    const float* __restrict__ W0, const float* __restrict__ W1,
    const float* __restrict__ W2, const float* __restrict__ W3,
    unsigned short* __restrict__ H0, unsigned short* __restrict__ L0,
    unsigned short* __restrict__ H1, unsigned short* __restrict__ L1,
    unsigned short* __restrict__ H2, unsigned short* __restrict__ L2,
    unsigned short* __restrict__ H3, unsigned short* __restrict__ L3) {
    int i = blockIdx.x * 256 + threadIdx.x;
    const float* W;
    unsigned short *H, *L;
    int local;
    if (i < 32768)       { W = W0; H = H0; L = L0; local = i; }
    else if (i < 65536)  { W = W1; H = H1; L = L1; local = i - 32768; }
    else if (i < 98304)  { W = W2; H = H2; L = L2; local = i - 65536; }
    else if (i < 114688) { W = W3; H = H3; L = L3; local = i - 98304; }
    else return;
    int k = local >> 7, c = local & 127;
    float w = W[local];
    unsigned short h = f2bf(w);
    unsigned short l = f2bf(w - bf2f(h));
    int d = (k >> 5) * 4096 + c * 32 + (k & 31);
    H[d] = h;
    L[d] = l;
}

// ---------------- split-bf16 MFMA GEMM: C[M,128] = A[M,K] @ W[K,128] + b ----------------
// BM=64 (625 blocks exact), BN=128, BK=32. 4 waves 2x2, wave = 32x64 = 2x4 frags 16x16.
// a*b ~= a_hi*b_hi + a_hi*b_lo + a_lo*b_hi  (3 MFMAs, fp32-like precision).

template <int KSTEPS, bool SPLIT, bool RELU>
__global__ __launch_bounds__(256) void gemm_mfma(
    const float* __restrict__ A0, const float* __restrict__ A1, int lda,
    const unsigned short* __restrict__ Bth, const unsigned short* __restrict__ Btl,
    const float* __restrict__ bias, float* __restrict__ C) {
    __shared__ unsigned short Ah[64 * 32], Al[64 * 32];
    __shared__ unsigned short Bh[128 * 32], Bl[128 * 32];
    int tid = threadIdx.x;
    int lane = tid & 63, wid = tid >> 6;
    int wr = wid >> 1, wc = wid & 1;
    int row0 = blockIdx.x * 64;

    f32x4 acc[2][4];
#pragma unroll
    for (int rt = 0; rt < 2; ++rt)
#pragma unroll
        for (int ct = 0; ct < 4; ++ct) acc[rt][ct] = 0.f;

    for (int s = 0; s < KSTEPS; ++s) {
        const float* Asrc = (!SPLIT || s < KSTEPS / 2) ? A0 : A1;
        int kbase = SPLIT ? (s & (KSTEPS / 2 - 1)) * 32 : s * 32;

        // stage A 64x32 f32 -> hi/lo bf16 (512 float4 chunks, 2 per thread)
#pragma unroll
        for (int i = 0; i < 2; ++i) {
            int cch = tid + i * 256;
            int r = cch >> 3, q = cch & 7;
            float4 v = *(const float4*)&Asrc[(size_t)(row0 + r) * lda + kbase + q * 4];
            ushort4 hh, ll;
            hh.x = f2bf(v.x); ll.x = f2bf(v.x - bf2f(hh.x));
            hh.y = f2bf(v.y); ll.y = f2bf(v.y - bf2f(hh.y));
            hh.z = f2bf(v.z); ll.z = f2bf(v.z - bf2f(hh.z));
            hh.w = f2bf(v.w); ll.w = f2bf(v.w - bf2f(hh.w));
            *(ushort4*)&Ah[r * 32 + q * 4] = hh;
            *(ushort4*)&Al[r * 32 + q * 4] = ll;
        }
        // stage B: contiguous 8KB copy per plane (pre-tiled/transposed)
        {
            const float4* sh4 = (const float4*)(Bth + s * 4096);
            const float4* sl4 = (const float4*)(Btl + s * 4096);
            float4* dh4 = (float4*)Bh;
            float4* dl4 = (float4*)Bl;
            dh4[tid] = sh4[tid];
            dh4[tid + 256] = sh4[tid + 256];
            dl4[tid] = sl4[tid];
            dl4[tid + 256] = sl4[tid + 256];
        }
        __syncthreads();

        bf16x8 afh[2], afl[2], bfh[4], bfl[4];
#pragma unroll
        for (int rt = 0; rt < 2; ++rt) {
            int off = (wr * 32 + rt * 16 + (lane & 15)) * 32 + (lane >> 4) * 8;
            afh[rt] = *(const bf16x8*)&Ah[off];
            afl[rt] = *(const bf16x8*)&Al[off];
        }
#pragma unroll
        for (int ct = 0; ct < 4; ++ct) {
            int off = (wc * 64 + ct * 16 + (lane & 15)) * 32 + (lane >> 4) * 8;
            bfh[ct] = *(const bf16x8*)&Bh[off];
            bfl[ct] = *(const bf16x8*)&Bl[off];
        }
#pragma unroll
        for (int rt = 0; rt < 2; ++rt)
#pragma unroll
            for (int ct = 0; ct < 4; ++ct) {
                acc[rt][ct] = __builtin_amdgcn_mfma_f32_16x16x32_bf16(afh[rt], bfh[ct], acc[rt][ct], 0, 0, 0);
                acc[rt][ct] = __builtin_amdgcn_mfma_f32_16x16x32_bf16(afh[rt], bfl[ct], acc[rt][ct], 0, 0, 0);
                acc[rt][ct] = __builtin_amdgcn_mfma_f32_16x16x32_bf16(afl[rt], bfh[ct], acc[rt][ct], 0, 0, 0);
            }
        __syncthreads();
    }

    // epilogue: D[row=(lane>>4)*4+reg][col=lane&15] per 16x16 frag
#pragma unroll
    for (int ct = 0; ct < 4; ++ct) {
        int col = wc * 64 + ct * 16 + (lane & 15);
        float bv = bias[col];
#pragma unroll
        for (int rt = 0; rt < 2; ++rt) {
#pragma unroll
            for (int r = 0; r < 4; ++r) {
                int row = row0 + wr * 32 + rt * 16 + (lane >> 4) * 4 + r;
                float v = acc[rt][ct][r] + bv;
                if (RELU) v = fmaxf(v, 0.f);
                C[(size_t)row * 128 + col] = v;
            }
        }
    }
}

// ---------------- launch ----------------

extern "C" void kernel_launch(void* const* d_in, const int* in_sizes, int n_in,
                              void* d_out, int out_size, void* d_ws, size_t ws_size,
                              hipStream_t stream) {
    const float* x     = (const float*)d_in[0];
    const float* W_in  = (const float*)d_in[1];
    const float* b_in  = (const float*)d_in[2];
    const float* W_m0  = (const float*)d_in[3];
    const float* b_m0  = (const float*)d_in[4];
    const float* W_m1  = (const float*)d_in[5];
    const float* b_m1  = (const float*)d_in[6];
    const float* W_o   = (const float*)d_in[7];
    const float* b_o   = (const float*)d_in[8];
    const int*   eidx  = (const int*)d_in[9];
    const int* src = eidx;
    const int* dst = eidx + N_EDGES;

    char* ws = (char*)d_ws;
    size_t off = 0;
    auto alloc = [&](size_t bytes) -> char* {
        char* p = ws + off;
        off += (bytes + 255) & ~(size_t)255;
        return p;
    };
    int* deg     = (int*)alloc((size_t)N_NODES * 4);
    int* row_off = (int*)alloc((size_t)(N_NODES + 1) * 4);
    int* cursor  = (int*)alloc((size_t)N_NODES * 4);
    int* csr     = (int*)alloc((size_t)N_EDGES * 4);
    int* bsum    = (int*)alloc(64 * 4);
    float* hA    = (float*)alloc((size_t)N_NODES * HID * 4);
    float* hB    = (float*)alloc((size_t)N_NODES * HID * 4);
    float* hC    = (float*)alloc((size_t)N_NODES * HID * 4);
    unsigned short* WinH = (unsigned short*)alloc(32768 * 2);
    unsigned short* WinL = (unsigned short*)alloc(32768 * 2);
    unsigned short* Wm0H = (unsigned short*)alloc(32768 * 2);
    unsigned short* Wm0L = (unsigned short*)alloc(32768 * 2);
    unsigned short* Wm1H = (unsigned short*)alloc(32768 * 2);
    unsigned short* Wm1L = (unsigned short*)alloc(32768 * 2);
    unsigned short* WoH  = (unsigned short*)alloc(16384 * 2);
    unsigned short* WoL  = (unsigned short*)alloc(16384 * 2);
    (void)ws_size;

    const int NB = (N_NODES + 1023) / 1024;  // 40

    hipMemsetAsync(deg, 0, (size_t)N_NODES * 4, stream);
    deg_count<<<(N_EDGES + 255) / 256, 256, 0, stream>>>(dst, deg, N_EDGES);
    block_sums<<<NB, 1024, 0, stream>>>(deg, bsum, N_NODES);
    scan_bsums<<<1, 64, 0, stream>>>(bsum, NB);
    write_offsets<<<NB, 1024, 0, stream>>>(deg, bsum, row_off, cursor, N_NODES);
    scatter_edges<<<(N_EDGES + 255) / 256, 256, 0, stream>>>(src, dst, cursor, csr, N_EDGES);

    prep_all<<<448, 256, 0, stream>>>(W_in, W_m0, W_m1, W_o,
                                      WinH, WinL, Wm0H, Wm0L, Wm1H, Wm1L, WoH, WoL);

    // h = relu(x @ W_in + b_in)
    gemm_mfma<8, false, true><<<625, 256, 0, stream>>>(x, nullptr, IN_DIM, WinH, WinL, b_in, hA);

    // layer 0
    agg_mean<<<10000, 256, 0, stream>>>(hA, row_off, csr, hB, N_NODES);
    agg_mean<<<10000, 256, 0, stream>>>(hB, row_off, csr, hC, N_NODES);
    gemm_mfma<8, true, true><<<625, 256, 0, stream>>>(hB, hC, HID, Wm0H, Wm0L, b_m0, hA);

    // layer 1
    agg_mean<<<10000, 256, 0, stream>>>(hA, row_off, csr, hB, N_NODES);
    agg_mean<<<10000, 256, 0, stream>>>(hB, row_off, csr, hC, N_NODES);
    gemm_mfma<8, true, false><<<625, 256, 0, stream>>>(hB, hC, HID, Wm1H, Wm1L, b_m1, hA);

    // out = h @ W_out + b_out
    gemm_mfma<4, false, false><<<625, 256, 0, stream>>>(hA, nullptr, HID, WoH, WoL, b_o, (float*)d_out);
}

// Round 6
// 249.571 us; speedup vs baseline: 2.0539x; 1.2439x over previous
//
#include <hip/hip_runtime.h>

#define N_NODES 40000
#define N_EDGES 640000
#define IN_DIM 256
#define HID 128

typedef short bf16x8 __attribute__((ext_vector_type(8)));
typedef float f32x4 __attribute__((ext_vector_type(4)));

__device__ __forceinline__ unsigned short f2bf(float f) {
    unsigned int u = __float_as_uint(f);
    unsigned int r = (u + 0x7FFFu + ((u >> 16) & 1u)) >> 16;
    return (unsigned short)r;
}
__device__ __forceinline__ float bf2f(unsigned short b) {
    return __uint_as_float(((unsigned int)b) << 16);
}

// ---------------- CSR build ----------------

__global__ void deg_count(const int* __restrict__ dst, int* __restrict__ deg, int E) {
    int e = blockIdx.x * 256 + threadIdx.x;
    if (e < E) atomicAdd(&deg[dst[e]], 1);
}

__global__ __launch_bounds__(1024) void block_sums(const int* __restrict__ deg,
                                                   int* __restrict__ bsum, int N) {
    __shared__ int sh[1024];
    int tid = threadIdx.x;
    int i = blockIdx.x * 1024 + tid;
    sh[tid] = (i < N) ? deg[i] : 0;
    __syncthreads();
#pragma unroll
    for (int off = 512; off > 0; off >>= 1) {
        if (tid < off) sh[tid] += sh[tid + off];
        __syncthreads();
    }
    if (tid == 0) bsum[blockIdx.x] = sh[0];
}

__global__ void scan_bsums(int* __restrict__ bsum, int nb) {
    if (threadIdx.x == 0 && blockIdx.x == 0) {
        int run = 0;
        for (int b = 0; b < nb; ++b) {
            int v = bsum[b];
            bsum[b] = run;
            run += v;
        }
    }
}

__global__ __launch_bounds__(1024) void write_offsets(const int* __restrict__ deg,
                                                      const int* __restrict__ bsum,
                                                      int* __restrict__ row_off,
                                                      int* __restrict__ cursor, int N) {
    __shared__ int sh[1024];
    int tid = threadIdx.x;
    int i = blockIdx.x * 1024 + tid;
    int v = (i < N) ? deg[i] : 0;
    sh[tid] = v;
    __syncthreads();
#pragma unroll
    for (int off = 1; off < 1024; off <<= 1) {
        int t = (tid >= off) ? sh[tid - off] : 0;
        __syncthreads();
        sh[tid] += t;
        __syncthreads();
    }
    int excl = sh[tid] - v + bsum[blockIdx.x];
    if (i < N) {
        row_off[i] = excl;
        cursor[i] = excl;
    }
    if (i == N - 1) row_off[N] = excl + v;
}

__global__ void scatter_edges(const int* __restrict__ src, const int* __restrict__ dst,
                              int* __restrict__ cursor, int* __restrict__ csr, int E) {
    int e = blockIdx.x * 256 + threadIdx.x;
    if (e < E) {
        int p = atomicAdd(&cursor[dst[e]], 1);
        csr[p] = src[e];
    }
}

// ---------------- mean aggregation (bf16 gather, fp32 accumulate) ----------------
// One wave per node. Lane halves take alternating edges; ushort4 (4 dims) per lane.
// Row = 256B contiguous. Output fp32 (for GEMM) + optional bf16 (for next agg).

template <bool OUT_BF16>
__global__ __launch_bounds__(256) void agg_mean_bf16(const unsigned short* __restrict__ hbf,
                                                     const int* __restrict__ row_off,
                                                     const int* __restrict__ csr,
                                                     float* __restrict__ out,
                                                     unsigned short* __restrict__ out_bf,
                                                     int N) {
    int node = blockIdx.x * 4 + (threadIdx.x >> 6);
    if (node >= N) return;
    int lane = threadIdx.x & 63;
    int half = lane >> 5;  // 0/1 -> alternating edges
    int sub = lane & 31;   // dims sub*4 .. sub*4+3
    int beg = row_off[node], end = row_off[node + 1];
    float4 a0 = make_float4(0.f, 0.f, 0.f, 0.f);
    float4 a1 = make_float4(0.f, 0.f, 0.f, 0.f);
    int e = beg;
    for (; e + 7 < end; e += 8) {
        int s0 = csr[e + half];
        int s1 = csr[e + 2 + half];
        int s2 = csr[e + 4 + half];
        int s3 = csr[e + 6 + half];
        ushort4 u0 = *(const ushort4*)&hbf[(size_t)s0 * HID + sub * 4];
        ushort4 u1 = *(const ushort4*)&hbf[(size_t)s1 * HID + sub * 4];
        ushort4 u2 = *(const ushort4*)&hbf[(size_t)s2 * HID + sub * 4];
        ushort4 u3 = *(const ushort4*)&hbf[(size_t)s3 * HID + sub * 4];
        a0.x += bf2f(u0.x) + bf2f(u2.x);
        a0.y += bf2f(u0.y) + bf2f(u2.y);
        a0.z += bf2f(u0.z) + bf2f(u2.z);
        a0.w += bf2f(u0.w) + bf2f(u2.w);
        a1.x += bf2f(u1.x) + bf2f(u3.x);
        a1.y += bf2f(u1.y) + bf2f(u3.y);
        a1.z += bf2f(u1.z) + bf2f(u3.z);
        a1.w += bf2f(u1.w) + bf2f(u3.w);
    }
    for (; e + half < end; e += 2) {
        int s = csr[e + half];
        ushort4 u = *(const ushort4*)&hbf[(size_t)s * HID + sub * 4];
        a0.x += bf2f(u.x);
        a0.y += bf2f(u.y);
        a0.z += bf2f(u.z);
        a0.w += bf2f(u.w);
    }
    float4 acc;
    acc.x = a0.x + a1.x;
    acc.y = a0.y + a1.y;
    acc.z = a0.z + a1.z;
    acc.w = a0.w + a1.w;
    acc.x += __shfl_xor(acc.x, 32);
    acc.y += __shfl_xor(acc.y, 32);
    acc.z += __shfl_xor(acc.z, 32);
    acc.w += __shfl_xor(acc.w, 32);
    if (half == 0) {
        float inv = 1.0f / fmaxf((float)(end - beg), 1.0f);
        acc.x *= inv;
        acc.y *= inv;
        acc.z *= inv;
        acc.w *= inv;
        *(float4*)&out[(size_t)node * HID + sub * 4] = acc;
        if (OUT_BF16) {
            ushort4 ub;
            ub.x = f2bf(acc.x);
            ub.y = f2bf(acc.y);
            ub.z = f2bf(acc.z);
            ub.w = f2bf(acc.w);
            *(ushort4*)&out_bf[(size_t)node * HID + sub * 4] = ub;
        }
    }
}

// ---------------- W prep: f32 [K][128] -> tiled transposed bf16 hi/lo ----------------
// dest[s][c][k'] (s = k>>5, k' = k&31): B-frag reads become lane-contiguous.

__global__ __launch_bounds__(256) void prep_all(
    const float* __restrict__ W0, const float* __restrict__ W1,
    const float* __restrict__ W2, const float* __restrict__ W3,
    unsigned short* __restrict__ H0, unsigned short* __restrict__ L0,
    unsigned short* __restrict__ H1, unsigned short* __restrict__ L1,
    unsigned short* __restrict__ H2, unsigned short* __restrict__ L2,
    unsigned short* __restrict__ H3, unsigned short* __restrict__ L3) {
    int i = blockIdx.x * 256 + threadIdx.x;
    const float* W;
    unsigned short *H, *L;
    int local;
    if (i < 32768)       { W = W0; H = H0; L = L0; local = i; }
    else if (i < 65536)  { W = W1; H = H1; L = L1; local = i - 32768; }
    else if (i < 98304)  { W = W2; H = H2; L = L2; local = i - 65536; }
    else if (i < 114688) { W = W3; H = H3; L = L3; local = i - 98304; }
    else return;
    int k = local >> 7, c = local & 127;
    float w = W[local];
    unsigned short h = f2bf(w);
    unsigned short l = f2bf(w - bf2f(h));
    int d = (k >> 5) * 4096 + c * 32 + (k & 31);
    H[d] = h;
    L[d] = l;
}

// ---------------- split-bf16 MFMA GEMM: C[M,128] = A[M,K] @ W[K,128] + b ----------------
// BM=64 (625 blocks exact), BN=128, BK=32. 4 waves 2x2, wave = 32x64 = 2x4 frags 16x16.
// a*b ~= a_hi*b_hi + a_hi*b_lo + a_lo*b_hi  (3 MFMAs, fp32-like precision).
// Output: fp32 (WF32) and/or bf16 (WBF16, for gather consumers).

template <int KSTEPS, bool SPLIT, bool RELU, bool WF32, bool WBF16>
__global__ __launch_bounds__(256) void gemm_mfma(
    const float* __restrict__ A0, const float* __restrict__ A1, int lda,
    const unsigned short* __restrict__ Bth, const unsigned short* __restrict__ Btl,
    const float* __restrict__ bias, float* __restrict__ C,
    unsigned short* __restrict__ Cbf) {
    __shared__ unsigned short Ah[64 * 32], Al[64 * 32];
    __shared__ unsigned short Bh[128 * 32], Bl[128 * 32];
    int tid = threadIdx.x;
    int lane = tid & 63, wid = tid >> 6;
    int wr = wid >> 1, wc = wid & 1;
    int row0 = blockIdx.x * 64;

    f32x4 acc[2][4];
#pragma unroll
    for (int rt = 0; rt < 2; ++rt)
#pragma unroll
        for (int ct = 0; ct < 4; ++ct) acc[rt][ct] = 0.f;

    for (int s = 0; s < KSTEPS; ++s) {
        const float* Asrc = (!SPLIT || s < KSTEPS / 2) ? A0 : A1;
        int kbase = SPLIT ? (s & (KSTEPS / 2 - 1)) * 32 : s * 32;

        // stage A 64x32 f32 -> hi/lo bf16 (512 float4 chunks, 2 per thread)
#pragma unroll
        for (int i = 0; i < 2; ++i) {
            int cch = tid + i * 256;
            int r = cch >> 3, q = cch & 7;
            float4 v = *(const float4*)&Asrc[(size_t)(row0 + r) * lda + kbase + q * 4];
            ushort4 hh, ll;
            hh.x = f2bf(v.x); ll.x = f2bf(v.x - bf2f(hh.x));
            hh.y = f2bf(v.y); ll.y = f2bf(v.y - bf2f(hh.y));
            hh.z = f2bf(v.z); ll.z = f2bf(v.z - bf2f(hh.z));
            hh.w = f2bf(v.w); ll.w = f2bf(v.w - bf2f(hh.w));
            *(ushort4*)&Ah[r * 32 + q * 4] = hh;
            *(ushort4*)&Al[r * 32 + q * 4] = ll;
        }
        // stage B: contiguous 8KB copy per plane (pre-tiled/transposed)
        {
            const float4* sh4 = (const float4*)(Bth + s * 4096);
            const float4* sl4 = (const float4*)(Btl + s * 4096);
            float4* dh4 = (float4*)Bh;
            float4* dl4 = (float4*)Bl;
            dh4[tid] = sh4[tid];
            dh4[tid + 256] = sh4[tid + 256];
            dl4[tid] = sl4[tid];
            dl4[tid + 256] = sl4[tid + 256];
        }
        __syncthreads();

        bf16x8 afh[2], afl[2], bfh[4], bfl[4];
#pragma unroll
        for (int rt = 0; rt < 2; ++rt) {
            int off = (wr * 32 + rt * 16 + (lane & 15)) * 32 + (lane >> 4) * 8;
            afh[rt] = *(const bf16x8*)&Ah[off];
            afl[rt] = *(const bf16x8*)&Al[off];
        }
#pragma unroll
        for (int ct = 0; ct < 4; ++ct) {
            int off = (wc * 64 + ct * 16 + (lane & 15)) * 32 + (lane >> 4) * 8;
            bfh[ct] = *(const bf16x8*)&Bh[off];
            bfl[ct] = *(const bf16x8*)&Bl[off];
        }
#pragma unroll
        for (int rt = 0; rt < 2; ++rt)
#pragma unroll
            for (int ct = 0; ct < 4; ++ct) {
                acc[rt][ct] = __builtin_amdgcn_mfma_f32_16x16x32_bf16(afh[rt], bfh[ct], acc[rt][ct], 0, 0, 0);
                acc[rt][ct] = __builtin_amdgcn_mfma_f32_16x16x32_bf16(afh[rt], bfl[ct], acc[rt][ct], 0, 0, 0);
                acc[rt][ct] = __builtin_amdgcn_mfma_f32_16x16x32_bf16(afl[rt], bfh[ct], acc[rt][ct], 0, 0, 0);
            }
        __syncthreads();
    }

    // epilogue: D[row=(lane>>4)*4+reg][col=lane&15] per 16x16 frag
#pragma unroll
    for (int ct = 0; ct < 4; ++ct) {
        int col = wc * 64 + ct * 16 + (lane & 15);
        float bv = bias[col];
#pragma unroll
        for (int rt = 0; rt < 2; ++rt) {
#pragma unroll
            for (int r = 0; r < 4; ++r) {
                int row = row0 + wr * 32 + rt * 16 + (lane >> 4) * 4 + r;
                float v = acc[rt][ct][r] + bv;
                if (RELU) v = fmaxf(v, 0.f);
                if (WF32) C[(size_t)row * 128 + col] = v;
                if (WBF16) Cbf[(size_t)row * 128 + col] = f2bf(v);
            }
        }
    }
}

// ---------------- launch ----------------

extern "C" void kernel_launch(void* const* d_in, const int* in_sizes, int n_in,
                              void* d_out, int out_size, void* d_ws, size_t ws_size,
                              hipStream_t stream) {
    const float* x     = (const float*)d_in[0];
    const float* W_in  = (const float*)d_in[1];
    const float* b_in  = (const float*)d_in[2];
    const float* W_m0  = (const float*)d_in[3];
    const float* b_m0  = (const float*)d_in[4];
    const float* W_m1  = (const float*)d_in[5];
    const float* b_m1  = (const float*)d_in[6];
    const float* W_o   = (const float*)d_in[7];
    const float* b_o   = (const float*)d_in[8];
    const int*   eidx  = (const int*)d_in[9];
    const int* src = eidx;
    const int* dst = eidx + N_EDGES;

    char* ws = (char*)d_ws;
    size_t off = 0;
    auto alloc = [&](size_t bytes) -> char* {
        char* p = ws + off;
        off += (bytes + 255) & ~(size_t)255;
        return p;
    };
    int* deg     = (int*)alloc((size_t)N_NODES * 4);
    int* row_off = (int*)alloc((size_t)(N_NODES + 1) * 4);
    int* cursor  = (int*)alloc((size_t)N_NODES * 4);
    int* csr     = (int*)alloc((size_t)N_EDGES * 4);
    int* bsum    = (int*)alloc(64 * 4);
    float* hA    = (float*)alloc((size_t)N_NODES * HID * 4);
    float* hB    = (float*)alloc((size_t)N_NODES * HID * 4);
    float* hC    = (float*)alloc((size_t)N_NODES * HID * 4);
    unsigned short* hbfA = (unsigned short*)alloc((size_t)N_NODES * HID * 2);
    unsigned short* hbfB = (unsigned short*)alloc((size_t)N_NODES * HID * 2);
    unsigned short* WinH = (unsigned short*)alloc(32768 * 2);
    unsigned short* WinL = (unsigned short*)alloc(32768 * 2);
    unsigned short* Wm0H = (unsigned short*)alloc(32768 * 2);
    unsigned short* Wm0L = (unsigned short*)alloc(32768 * 2);
    unsigned short* Wm1H = (unsigned short*)alloc(32768 * 2);
    unsigned short* Wm1L = (unsigned short*)alloc(32768 * 2);
    unsigned short* WoH  = (unsigned short*)alloc(16384 * 2);
    unsigned short* WoL  = (unsigned short*)alloc(16384 * 2);
    (void)ws_size;

    const int NB = (N_NODES + 1023) / 1024;  // 40

    hipMemsetAsync(deg, 0, (size_t)N_NODES * 4, stream);
    deg_count<<<(N_EDGES + 255) / 256, 256, 0, stream>>>(dst, deg, N_EDGES);
    block_sums<<<NB, 1024, 0, stream>>>(deg, bsum, N_NODES);
    scan_bsums<<<1, 64, 0, stream>>>(bsum, NB);
    write_offsets<<<NB, 1024, 0, stream>>>(deg, bsum, row_off, cursor, N_NODES);
    scatter_edges<<<(N_EDGES + 255) / 256, 256, 0, stream>>>(src, dst, cursor, csr, N_EDGES);

    prep_all<<<448, 256, 0, stream>>>(W_in, W_m0, W_m1, W_o,
                                      WinH, WinL, Wm0H, Wm0L, Wm1H, Wm1L, WoH, WoL);

    // h = relu(x @ W_in + b_in) -> bf16 only (consumed by gathers)
    gemm_mfma<8, false, true, false, true><<<625, 256, 0, stream>>>(
        x, nullptr, IN_DIM, WinH, WinL, b_in, nullptr, hbfA);

    // layer 0
    agg_mean_bf16<true><<<10000, 256, 0, stream>>>(hbfA, row_off, csr, hB, hbfB, N_NODES);
    agg_mean_bf16<false><<<10000, 256, 0, stream>>>(hbfB, row_off, csr, hC, nullptr, N_NODES);
    gemm_mfma<8, true, true, false, true><<<625, 256, 0, stream>>>(
        hB, hC, HID, Wm0H, Wm0L, b_m0, nullptr, hbfA);

    // layer 1
    agg_mean_bf16<true><<<10000, 256, 0, stream>>>(hbfA, row_off, csr, hB, hbfB, N_NODES);
    agg_mean_bf16<false><<<10000, 256, 0, stream>>>(hbfB, row_off, csr, hC, nullptr, N_NODES);
    gemm_mfma<8, true, false, true, false><<<625, 256, 0, stream>>>(
        hB, hC, HID, Wm1H, Wm1L, b_m1, hA, nullptr);

    // out = h @ W_out + b_out (fp32 A, full precision)
    gemm_mfma<4, false, false, true, false><<<625, 256, 0, stream>>>(
        hA, nullptr, HID, WoH, WoL, b_o, (float*)d_out, nullptr);
}

// Round 8
// 229.422 us; speedup vs baseline: 2.2343x; 1.0878x over previous
//
#include <hip/hip_runtime.h>

#define N_NODES 40000
#define N_EDGES 640000
#define IN_DIM 256
#define HID 128

typedef short bf16x8 __attribute__((ext_vector_type(8)));
typedef float f32x4 __attribute__((ext_vector_type(4)));

__device__ __forceinline__ unsigned short f2bf(float f) {
    unsigned int u = __float_as_uint(f);
    unsigned int r = (u + 0x7FFFu + ((u >> 16) & 1u)) >> 16;
    return (unsigned short)r;
}
__device__ __forceinline__ float bf2f(unsigned short b) {
    return __uint_as_float(((unsigned int)b) << 16);
}

// ---------------- fused front: deg_count (blocks 0..2499) + W prep (blocks 2500+) ----------------
// prep: f32 [K][128] -> tiled transposed bf16 hi/lo planes, dest[s][c][k'] (s=k>>5,k'=k&31).

__global__ __launch_bounds__(256) void front_kernel(
    const int* __restrict__ dst, int* __restrict__ deg, int E,
    const float* __restrict__ W0, const float* __restrict__ W1,
    const float* __restrict__ W2, const float* __restrict__ W3,
    unsigned short* __restrict__ H0, unsigned short* __restrict__ L0,
    unsigned short* __restrict__ H1, unsigned short* __restrict__ L1,
    unsigned short* __restrict__ H2, unsigned short* __restrict__ L2,
    unsigned short* __restrict__ H3, unsigned short* __restrict__ L3) {
    int bid = blockIdx.x;
    if (bid < 2500) {
        int e = bid * 256 + threadIdx.x;
        if (e < E) atomicAdd(&deg[dst[e]], 1);
        return;
    }
    int i = (bid - 2500) * 256 + threadIdx.x;
    const float* W;
    unsigned short *H, *L;
    int local;
    if (i < 32768)       { W = W0; H = H0; L = L0; local = i; }
    else if (i < 65536)  { W = W1; H = H1; L = L1; local = i - 32768; }
    else if (i < 98304)  { W = W2; H = H2; L = L2; local = i - 65536; }
    else if (i < 114688) { W = W3; H = H3; L = L3; local = i - 98304; }
    else return;
    int k = local >> 7, c = local & 127;
    float w = W[local];
    unsigned short h = f2bf(w);
    unsigned short l = f2bf(w - bf2f(h));
    int d = (k >> 5) * 4096 + c * 32 + (k & 31);
    H[d] = h;
    L[d] = l;
}

// ---------------- CSR scan ----------------

__global__ __launch_bounds__(1024) void block_sums(const int* __restrict__ deg,
                                                   int* __restrict__ bsum, int N) {
    __shared__ int sh[1024];
    int tid = threadIdx.x;
    int i = blockIdx.x * 1024 + tid;
    sh[tid] = (i < N) ? deg[i] : 0;
    __syncthreads();
#pragma unroll
    for (int off = 512; off > 0; off >>= 1) {
        if (tid < off) sh[tid] += sh[tid + off];
        __syncthreads();
    }
    if (tid == 0) bsum[blockIdx.x] = sh[0];
}

// Block-local exclusive scan; block base = reduce of bsum[0..bid-1] (correct descending tree).
__global__ __launch_bounds__(1024) void write_offsets(const int* __restrict__ deg,
                                                      const int* __restrict__ bsum,
                                                      int* __restrict__ row_off,
                                                      int* __restrict__ cursor, int N) {
    __shared__ int sh[1024];
    __shared__ int shb[64];
    int tid = threadIdx.x;
    int bid = blockIdx.x;
    int i = bid * 1024 + tid;
    int v = (i < N) ? deg[i] : 0;
    sh[tid] = v;
    if (tid < 64) shb[tid] = (tid < bid) ? bsum[tid] : 0;  // bid <= 39
    __syncthreads();
    // reduce shb[0..63] -> shb[0]
#pragma unroll
    for (int o = 32; o > 0; o >>= 1) {
        if (tid < o) shb[tid] += shb[tid + o];
        __syncthreads();
    }
#pragma unroll
    for (int off = 1; off < 1024; off <<= 1) {
        int t = (tid >= off) ? sh[tid - off] : 0;
        __syncthreads();
        sh[tid] += t;
        __syncthreads();
    }
    int base = shb[0];
    int excl = sh[tid] - v + base;
    if (i < N) {
        row_off[i] = excl;
        cursor[i] = excl;
    }
    if (i == N - 1) row_off[N] = excl + v;
}

__global__ void scatter_edges(const int* __restrict__ src, const int* __restrict__ dst,
                              int* __restrict__ cursor, int* __restrict__ csr, int E) {
    int e = blockIdx.x * 256 + threadIdx.x;
    if (e < E) {
        int p = atomicAdd(&cursor[dst[e]], 1);
        csr[p] = src[e];
    }
}

// ---------------- mean aggregation (bf16 gather, fp32 accumulate, bf16 out) ----------------

__global__ __launch_bounds__(256) void agg_mean_bf(const unsigned short* __restrict__ hbf,
                                                   const int* __restrict__ row_off,
                                                   const int* __restrict__ csr,
                                                   unsigned short* __restrict__ out_bf,
                                                   int N) {
    int node = blockIdx.x * 4 + (threadIdx.x >> 6);
    if (node >= N) return;
    int lane = threadIdx.x & 63;
    int half = lane >> 5;  // 0/1 -> alternating edges
    int sub = lane & 31;   // dims sub*4 .. sub*4+3
    int beg = row_off[node], end = row_off[node + 1];
    float4 a0 = make_float4(0.f, 0.f, 0.f, 0.f);
    float4 a1 = make_float4(0.f, 0.f, 0.f, 0.f);
    int e = beg;
    for (; e + 7 < end; e += 8) {
        int s0 = csr[e + half];
        int s1 = csr[e + 2 + half];
        int s2 = csr[e + 4 + half];
        int s3 = csr[e + 6 + half];
        ushort4 u0 = *(const ushort4*)&hbf[(size_t)s0 * HID + sub * 4];
        ushort4 u1 = *(const ushort4*)&hbf[(size_t)s1 * HID + sub * 4];
        ushort4 u2 = *(const ushort4*)&hbf[(size_t)s2 * HID + sub * 4];
        ushort4 u3 = *(const ushort4*)&hbf[(size_t)s3 * HID + sub * 4];
        a0.x += bf2f(u0.x) + bf2f(u2.x);
        a0.y += bf2f(u0.y) + bf2f(u2.y);
        a0.z += bf2f(u0.z) + bf2f(u2.z);
        a0.w += bf2f(u0.w) + bf2f(u2.w);
        a1.x += bf2f(u1.x) + bf2f(u3.x);
        a1.y += bf2f(u1.y) + bf2f(u3.y);
        a1.z += bf2f(u1.z) + bf2f(u3.z);
        a1.w += bf2f(u1.w) + bf2f(u3.w);
    }
    for (; e + half < end; e += 2) {
        int s = csr[e + half];
        ushort4 u = *(const ushort4*)&hbf[(size_t)s * HID + sub * 4];
        a0.x += bf2f(u.x);
        a0.y += bf2f(u.y);
        a0.z += bf2f(u.z);
        a0.w += bf2f(u.w);
    }
    float4 acc;
    acc.x = a0.x + a1.x;
    acc.y = a0.y + a1.y;
    acc.z = a0.z + a1.z;
    acc.w = a0.w + a1.w;
    acc.x += __shfl_xor(acc.x, 32);
    acc.y += __shfl_xor(acc.y, 32);
    acc.z += __shfl_xor(acc.z, 32);
    acc.w += __shfl_xor(acc.w, 32);
    if (half == 0) {
        float inv = 1.0f / fmaxf((float)(end - beg), 1.0f);
        ushort4 ub;
        ub.x = f2bf(acc.x * inv);
        ub.y = f2bf(acc.y * inv);
        ub.z = f2bf(acc.z * inv);
        ub.w = f2bf(acc.w * inv);
        *(ushort4*)&out_bf[(size_t)node * HID + sub * 4] = ub;
    }
}

// ---------------- split-bf16 MFMA GEMM (fp32 A): C = A @ W + b ----------------
// BM=64, BN=128, BK=32. 4 waves 2x2, wave = 32x64 = 2x4 frags of 16x16x32.
// a*b ~= a_hi*b_hi + a_hi*b_lo + a_lo*b_hi (3 MFMAs).

template <int KSTEPS, bool RELU, bool WF32, bool WBF16>
__global__ __launch_bounds__(256) void gemm_mfma(
    const float* __restrict__ A0, int lda,
    const unsigned short* __restrict__ Bth, const unsigned short* __restrict__ Btl,
    const float* __restrict__ bias, float* __restrict__ C,
    unsigned short* __restrict__ Cbf) {
    __shared__ unsigned short Ah[64 * 32], Al[64 * 32];
    __shared__ unsigned short Bh[128 * 32], Bl[128 * 32];
    int tid = threadIdx.x;
    int lane = tid & 63, wid = tid >> 6;
    int wr = wid >> 1, wc = wid & 1;
    int row0 = blockIdx.x * 64;

    f32x4 acc[2][4];
#pragma unroll
    for (int rt = 0; rt < 2; ++rt)
#pragma unroll
        for (int ct = 0; ct < 4; ++ct) acc[rt][ct] = 0.f;

    for (int s = 0; s < KSTEPS; ++s) {
        int kbase = s * 32;
        // stage A 64x32 f32 -> hi/lo bf16
#pragma unroll
        for (int i = 0; i < 2; ++i) {
            int cch = tid + i * 256;
            int r = cch >> 3, q = cch & 7;
            float4 v = *(const float4*)&A0[(size_t)(row0 + r) * lda + kbase + q * 4];
            ushort4 hh, ll;
            hh.x = f2bf(v.x); ll.x = f2bf(v.x - bf2f(hh.x));
            hh.y = f2bf(v.y); ll.y = f2bf(v.y - bf2f(hh.y));
            hh.z = f2bf(v.z); ll.z = f2bf(v.z - bf2f(hh.z));
            hh.w = f2bf(v.w); ll.w = f2bf(v.w - bf2f(hh.w));
            *(ushort4*)&Ah[r * 32 + q * 4] = hh;
            *(ushort4*)&Al[r * 32 + q * 4] = ll;
        }
        // stage B: contiguous 8KB copy per plane (pre-tiled/transposed)
        {
            const float4* sh4 = (const float4*)(Bth + s * 4096);
            const float4* sl4 = (const float4*)(Btl + s * 4096);
            float4* dh4 = (float4*)Bh;
            float4* dl4 = (float4*)Bl;
            dh4[tid] = sh4[tid];
            dh4[tid + 256] = sh4[tid + 256];
            dl4[tid] = sl4[tid];
            dl4[tid + 256] = sl4[tid + 256];
        }
        __syncthreads();

        bf16x8 afh[2], afl[2], bfh[4], bfl[4];
#pragma unroll
        for (int rt = 0; rt < 2; ++rt) {
            int off = (wr * 32 + rt * 16 + (lane & 15)) * 32 + (lane >> 4) * 8;
            afh[rt] = *(const bf16x8*)&Ah[off];
            afl[rt] = *(const bf16x8*)&Al[off];
        }
#pragma unroll
        for (int ct = 0; ct < 4; ++ct) {
            int off = (wc * 64 + ct * 16 + (lane & 15)) * 32 + (lane >> 4) * 8;
            bfh[ct] = *(const bf16x8*)&Bh[off];
            bfl[ct] = *(const bf16x8*)&Bl[off];
        }
#pragma unroll
        for (int rt = 0; rt < 2; ++rt)
#pragma unroll
            for (int ct = 0; ct < 4; ++ct) {
                acc[rt][ct] = __builtin_amdgcn_mfma_f32_16x16x32_bf16(afh[rt], bfh[ct], acc[rt][ct], 0, 0, 0);
                acc[rt][ct] = __builtin_amdgcn_mfma_f32_16x16x32_bf16(afh[rt], bfl[ct], acc[rt][ct], 0, 0, 0);
                acc[rt][ct] = __builtin_amdgcn_mfma_f32_16x16x32_bf16(afl[rt], bfh[ct], acc[rt][ct], 0, 0, 0);
            }
        __syncthreads();
    }

#pragma unroll
    for (int ct = 0; ct < 4; ++ct) {
        int col = wc * 64 + ct * 16 + (lane & 15);
        float bv = bias[col];
#pragma unroll
        for (int rt = 0; rt < 2; ++rt) {
#pragma unroll
            for (int r = 0; r < 4; ++r) {
                int row = row0 + wr * 32 + rt * 16 + (lane >> 4) * 4 + r;
                float v = acc[rt][ct][r] + bv;
                if (RELU) v = fmaxf(v, 0.f);
                if (WF32) C[(size_t)row * 128 + col] = v;
                if (WBF16) Cbf[(size_t)row * 128 + col] = f2bf(v);
            }
        }
    }
}

// ---------------- bf16-A MFMA GEMM (mix layers): C = [A0|A1] @ W + b ----------------
// A operands are bf16 [N][128]; W split hi/lo (2 MFMAs per frag).

template <bool RELU, bool WF32, bool WBF16>
__global__ __launch_bounds__(256) void gemm_a16(
    const unsigned short* __restrict__ A0, const unsigned short* __restrict__ A1,
    const unsigned short* __restrict__ Bth, const unsigned short* __restrict__ Btl,
    const float* __restrict__ bias, float* __restrict__ C,
    unsigned short* __restrict__ Cbf) {
    __shared__ unsigned short Ab[64 * 32];
    __shared__ unsigned short Bh[128 * 32], Bl[128 * 32];
    int tid = threadIdx.x;
    int lane = tid & 63, wid = tid >> 6;
    int wr = wid >> 1, wc = wid & 1;
    int row0 = blockIdx.x * 64;

    f32x4 acc[2][4];
#pragma unroll
    for (int rt = 0; rt < 2; ++rt)
#pragma unroll
        for (int ct = 0; ct < 4; ++ct) acc[rt][ct] = 0.f;

    for (int s = 0; s < 8; ++s) {
        const unsigned short* Asrc = (s < 4) ? A0 : A1;
        int kbase = (s & 3) * 32;
        // stage A 64x32 bf16: 4KB, 256 threads x 16B
        {
            int r = tid >> 2, q = (tid & 3) * 8;
            *(float4*)&Ab[r * 32 + q] =
                *(const float4*)&Asrc[(size_t)(row0 + r) * HID + kbase + q];
        }
        // stage B
        {
            const float4* sh4 = (const float4*)(Bth + s * 4096);
            const float4* sl4 = (const float4*)(Btl + s * 4096);
            float4* dh4 = (float4*)Bh;
            float4* dl4 = (float4*)Bl;
            dh4[tid] = sh4[tid];
            dh4[tid + 256] = sh4[tid + 256];
            dl4[tid] = sl4[tid];
            dl4[tid + 256] = sl4[tid + 256];
        }
        __syncthreads();

        bf16x8 af[2], bfh[4], bfl[4];
#pragma unroll
        for (int rt = 0; rt < 2; ++rt) {
            int off = (wr * 32 + rt * 16 + (lane & 15)) * 32 + (lane >> 4) * 8;
            af[rt] = *(const bf16x8*)&Ab[off];
        }
#pragma unroll
        for (int ct = 0; ct < 4; ++ct) {
            int off = (wc * 64 + ct * 16 + (lane & 15)) * 32 + (lane >> 4) * 8;
            bfh[ct] = *(const bf16x8*)&Bh[off];
            bfl[ct] = *(const bf16x8*)&Bl[off];
        }
#pragma unroll
        for (int rt = 0; rt < 2; ++rt)
#pragma unroll
            for (int ct = 0; ct < 4; ++ct) {
                acc[rt][ct] = __builtin_amdgcn_mfma_f32_16x16x32_bf16(af[rt], bfh[ct], acc[rt][ct], 0, 0, 0);
                acc[rt][ct] = __builtin_amdgcn_mfma_f32_16x16x32_bf16(af[rt], bfl[ct], acc[rt][ct], 0, 0, 0);
            }
        __syncthreads();
    }

#pragma unroll
    for (int ct = 0; ct < 4; ++ct) {
        int col = wc * 64 + ct * 16 + (lane & 15);
        float bv = bias[col];
#pragma unroll
        for (int rt = 0; rt < 2; ++rt) {
#pragma unroll
            for (int r = 0; r < 4; ++r) {
                int row = row0 + wr * 32 + rt * 16 + (lane >> 4) * 4 + r;
                float v = acc[rt][ct][r] + bv;
                if (RELU) v = fmaxf(v, 0.f);
                if (WF32) C[(size_t)row * 128 + col] = v;
                if (WBF16) Cbf[(size_t)row * 128 + col] = f2bf(v);
            }
        }
    }
}

// ---------------- launch ----------------

extern "C" void kernel_launch(void* const* d_in, const int* in_sizes, int n_in,
                              void* d_out, int out_size, void* d_ws, size_t ws_size,
                              hipStream_t stream) {
    const float* x     = (const float*)d_in[0];
    const float* W_in  = (const float*)d_in[1];
    const float* b_in  = (const float*)d_in[2];
    const float* W_m0  = (const float*)d_in[3];
    const float* b_m0  = (const float*)d_in[4];
    const float* W_m1  = (const float*)d_in[5];
    const float* b_m1  = (const float*)d_in[6];
    const float* W_o   = (const float*)d_in[7];
    const float* b_o   = (const float*)d_in[8];
    const int*   eidx  = (const int*)d_in[9];
    const int* src = eidx;
    const int* dst = eidx + N_EDGES;

    char* ws = (char*)d_ws;
    size_t off = 0;
    auto alloc = [&](size_t bytes) -> char* {
        char* p = ws + off;
        off += (bytes + 255) & ~(size_t)255;
        return p;
    };
    int* deg     = (int*)alloc((size_t)N_NODES * 4);
    int* row_off = (int*)alloc((size_t)(N_NODES + 1) * 4);
    int* cursor  = (int*)alloc((size_t)N_NODES * 4);
    int* csr     = (int*)alloc((size_t)N_EDGES * 4);
    int* bsum    = (int*)alloc(64 * 4);
    float* hA    = (float*)alloc((size_t)N_NODES * HID * 4);
    unsigned short* hbf1 = (unsigned short*)alloc((size_t)N_NODES * HID * 2);
    unsigned short* hbf2 = (unsigned short*)alloc((size_t)N_NODES * HID * 2);
    unsigned short* hbf3 = (unsigned short*)alloc((size_t)N_NODES * HID * 2);
    unsigned short* WinH = (unsigned short*)alloc(32768 * 2);
    unsigned short* WinL = (unsigned short*)alloc(32768 * 2);
    unsigned short* Wm0H = (unsigned short*)alloc(32768 * 2);
    unsigned short* Wm0L = (unsigned short*)alloc(32768 * 2);
    unsigned short* Wm1H = (unsigned short*)alloc(32768 * 2);
    unsigned short* Wm1L = (unsigned short*)alloc(32768 * 2);
    unsigned short* WoH  = (unsigned short*)alloc(16384 * 2);
    unsigned short* WoL  = (unsigned short*)alloc(16384 * 2);
    (void)ws_size;

    const int NB = (N_NODES + 1023) / 1024;  // 40

    hipMemsetAsync(deg, 0, (size_t)N_NODES * 4, stream);
    front_kernel<<<2500 + 448, 256, 0, stream>>>(dst, deg, N_EDGES,
                                                 W_in, W_m0, W_m1, W_o,
                                                 WinH, WinL, Wm0H, Wm0L,
                                                 Wm1H, Wm1L, WoH, WoL);
    block_sums<<<NB, 1024, 0, stream>>>(deg, bsum, N_NODES);
    write_offsets<<<NB, 1024, 0, stream>>>(deg, bsum, row_off, cursor, N_NODES);
    scatter_edges<<<(N_EDGES + 255) / 256, 256, 0, stream>>>(src, dst, cursor, csr, N_EDGES);

    // h = relu(x @ W_in + b_in) -> bf16
    gemm_mfma<8, true, false, true><<<625, 256, 0, stream>>>(
        x, IN_DIM, WinH, WinL, b_in, nullptr, hbf1);

    // layer 0
    agg_mean_bf<<<10000, 256, 0, stream>>>(hbf1, row_off, csr, hbf2, N_NODES);
    agg_mean_bf<<<10000, 256, 0, stream>>>(hbf2, row_off, csr, hbf3, N_NODES);
    gemm_a16<true, false, true><<<625, 256, 0, stream>>>(
        hbf2, hbf3, Wm0H, Wm0L, b_m0, nullptr, hbf1);

    // layer 1
    agg_mean_bf<<<10000, 256, 0, stream>>>(hbf1, row_off, csr, hbf2, N_NODES);
    agg_mean_bf<<<10000, 256, 0, stream>>>(hbf2, row_off, csr, hbf3, N_NODES);
    gemm_a16<false, true, false><<<625, 256, 0, stream>>>(
        hbf2, hbf3, Wm1H, Wm1L, b_m1, hA, nullptr);

    // out = h @ W_out + b_out (fp32 A, full split precision)
    gemm_mfma<4, false, true, false><<<625, 256, 0, stream>>>(
        hA, HID, WoH, WoL, b_o, (float*)d_out, nullptr);
}